// Round 4
// baseline (227.999 us; speedup 1.0000x reference)
//
#include <hip/hip_runtime.h>
#include <hip/hip_bf16.h>

#define D 128
#define NH 4
#define NEG_SLOPE 0.2f
#define LN_EPS 1e-5f

typedef __attribute__((ext_vector_type(4))) float f32x4;
typedef __attribute__((ext_vector_type(8))) short bf16x8;

__device__ __forceinline__ float bf2f(unsigned short u) {
  union { unsigned int i; float f; } c; c.i = ((unsigned int)u) << 16; return c.f;
}
__device__ __forceinline__ float bflo(unsigned int u) {
  union { unsigned int i; float f; } c; c.i = u << 16; return c.f;
}
__device__ __forceinline__ float bfhi(unsigned int u) {
  union { unsigned int i; float f; } c; c.i = u & 0xFFFF0000u; return c.f;
}
__device__ __forceinline__ unsigned short f2bf(float f) {
  union { float f; unsigned int i; } c; c.f = f;
  unsigned int r = c.i + 0x7FFFu + ((c.i >> 16) & 1u);  // RNE
  return (unsigned short)(r >> 16);
}

// ---------------- W prep: Wt[c][k] = W'[k][c] in bf16, c = h*128+f | 512+f ----
__global__ __launch_bounds__(128) void k_prep_w(
    const float* __restrict__ Wgat, const float* __restrict__ Wgcn,
    unsigned short* __restrict__ Wt)
{
  int c = blockIdx.x;     // 0..639
  int k = threadIdx.x;    // 0..127
  float v;
  if (c < 512) { int h = c >> 7, f = c & 127; v = Wgat[((size_t)h * D + k) * D + f]; }
  else         { v = Wgcn[(size_t)k * D + (c - 512)]; }
  Wt[(size_t)c * D + k] = f2bf(v);
}

// ---------------- MFMA GEMM: X[30000x128] @ W'[128x640] -------------------------
// xh interleaved [n][d][h] bf16; xg [n][d] bf16. grid (235, 10).
__global__ __launch_bounds__(256) void k_gemm_mfma(
    const float* __restrict__ x, const unsigned short* __restrict__ Wt,
    unsigned short* __restrict__ xh, unsigned short* __restrict__ xg, int N)
{
  __shared__ unsigned short As[128 * 128];  // [row][k], 16B-block kb ^= row&7
  __shared__ unsigned short Bs[64 * 128];   // [col][k], 16B-block kb ^= col&7
  const int t = threadIdx.x;
  const int m0 = blockIdx.x * 128;
  const int c0 = blockIdx.y * 64;

  #pragma unroll
  for (int i = 0; i < 16; ++i) {
    int f = i * 256 + t;          // float4 index
    int row = f >> 5;             // 0..127
    int k4 = (f & 31) * 4;        // 0,4,...,124
    int gm = m0 + row;
    float4 v = (gm < N) ? *(const float4*)&x[(size_t)gm * D + k4]
                        : make_float4(0.f, 0.f, 0.f, 0.f);
    ushort4 b;
    b.x = f2bf(v.x); b.y = f2bf(v.y); b.z = f2bf(v.z); b.w = f2bf(v.w);
    int kb = k4 >> 3, ko = k4 & 7;
    *(ushort4*)&As[row * 128 + ((kb ^ (row & 7)) << 3) + ko] = b;
  }
  #pragma unroll
  for (int i = 0; i < 4; ++i) {
    int g = i * 256 + t;          // 16B-block index
    int col = g >> 4;             // 0..63
    int kb = g & 15;
    uint4 v = *(const uint4*)&Wt[(size_t)(c0 + col) * D + kb * 8];
    *(uint4*)&Bs[col * 128 + ((kb ^ (col & 7)) << 3)] = v;
  }
  __syncthreads();

  const int w = t >> 6, l = t & 63;
  const int wr = w >> 1, wc = w & 1;
  const int lrow = l & 15, lk = l >> 4;

  f32x4 acc[4][2];
  #pragma unroll
  for (int m = 0; m < 4; ++m)
    #pragma unroll
    for (int n = 0; n < 2; ++n) acc[m][n] = (f32x4){0.f, 0.f, 0.f, 0.f};

  #pragma unroll
  for (int ks = 0; ks < 4; ++ks) {
    int kb = ks * 4 + lk;
    bf16x8 a[4], b[2];
    #pragma unroll
    for (int m = 0; m < 4; ++m) {
      int row = wr * 64 + m * 16 + lrow;
      a[m] = *(const bf16x8*)&As[row * 128 + ((kb ^ (row & 7)) << 3)];
    }
    #pragma unroll
    for (int n = 0; n < 2; ++n) {
      int col = wc * 32 + n * 16 + lrow;
      b[n] = *(const bf16x8*)&Bs[col * 128 + ((kb ^ (col & 7)) << 3)];
    }
    #pragma unroll
    for (int m = 0; m < 4; ++m)
      #pragma unroll
      for (int n = 0; n < 2; ++n)
        acc[m][n] = __builtin_amdgcn_mfma_f32_16x16x32_bf16(a[m], b[n], acc[m][n], 0, 0, 0);
  }

  const bool is_gat = (c0 < 512);
  const int h = c0 >> 7;
  #pragma unroll
  for (int m = 0; m < 4; ++m) {
    #pragma unroll
    for (int n = 0; n < 2; ++n) {
      int c = c0 + wc * 32 + n * 16 + lrow;
      #pragma unroll
      for (int j = 0; j < 4; ++j) {
        int r = m0 + wr * 64 + m * 16 + lk * 4 + j;
        if (r >= N) continue;
        unsigned short bv = f2bf(acc[m][n][j]);
        if (is_gat) xh[((size_t)r * D + (c & 127)) * NH + h] = bv;
        else        xg[(size_t)r * D + (c - 512)] = bv;
      }
    }
  }
}

// ---------------- per-node attention dots from interleaved xh -------------------
__global__ __launch_bounds__(256) void k_att(
    const unsigned short* __restrict__ xh,
    const float* __restrict__ att_src, const float* __restrict__ att_dst,
    float* __restrict__ a_s, float* __restrict__ a_d, int N)
{
  const int w = threadIdx.x >> 6, l = threadIdx.x & 63;
  const int n = blockIdx.x * 4 + w;
  if (n >= N) return;
  const uint4 v = *(const uint4*)(xh + ((size_t)n << 9) + (l << 3)); // dims 2l,2l+1
  float x00 = bflo(v.x), x01 = bfhi(v.x), x02 = bflo(v.y), x03 = bfhi(v.y);
  float x10 = bflo(v.z), x11 = bfhi(v.z), x12 = bflo(v.w), x13 = bfhi(v.w);
  float2 as0 = ((const float2*)(att_src))[l];
  float2 as1 = ((const float2*)(att_src + D))[l];
  float2 as2 = ((const float2*)(att_src + 2 * D))[l];
  float2 as3 = ((const float2*)(att_src + 3 * D))[l];
  float2 ad0 = ((const float2*)(att_dst))[l];
  float2 ad1 = ((const float2*)(att_dst + D))[l];
  float2 ad2 = ((const float2*)(att_dst + 2 * D))[l];
  float2 ad3 = ((const float2*)(att_dst + 3 * D))[l];
  float s0 = x00 * as0.x + x10 * as0.y;
  float s1 = x01 * as1.x + x11 * as1.y;
  float s2 = x02 * as2.x + x12 * as2.y;
  float s3 = x03 * as3.x + x13 * as3.y;
  float d0 = x00 * ad0.x + x10 * ad0.y;
  float d1 = x01 * ad1.x + x11 * ad1.y;
  float d2 = x02 * ad2.x + x12 * ad2.y;
  float d3 = x03 * ad3.x + x13 * ad3.y;
  #pragma unroll
  for (int off = 32; off; off >>= 1) {
    s0 += __shfl_xor(s0, off); s1 += __shfl_xor(s1, off);
    s2 += __shfl_xor(s2, off); s3 += __shfl_xor(s3, off);
    d0 += __shfl_xor(d0, off); d1 += __shfl_xor(d1, off);
    d2 += __shfl_xor(d2, off); d3 += __shfl_xor(d3, off);
  }
  if (l == 0) {
    ((float4*)a_s)[n] = make_float4(s0, s1, s2, s3);
    ((float4*)a_d)[n] = make_float4(d0, d1, d2, d3);
  }
}

// ---------------- CSR build ----------------------------------------------------
__global__ void k_deg(const int* __restrict__ ei, int E, int N, int* __restrict__ deg)
{
  int e = blockIdx.x * blockDim.x + threadIdx.x;
  if (e >= E + N) return;
  int dst = (e < E) ? ei[E + e] : (e - E);
  atomicAdd(&deg[dst], 1);
}

__global__ void k_scan1(const int* __restrict__ deg, int N, int* __restrict__ bsum)
{
  __shared__ int s[256];
  int t = threadIdx.x;
  int i = blockIdx.x * 256 + t;
  s[t] = (i < N) ? deg[i] : 0;
  __syncthreads();
  for (int off = 128; off; off >>= 1) {
    if (t < off) s[t] += s[t + off];
    __syncthreads();
  }
  if (t == 0) bsum[blockIdx.x] = s[0];
}

__global__ void k_scan2(int* __restrict__ bsum, int nb)
{
  __shared__ int s[128];
  int t = threadIdx.x;
  int v = (t < nb) ? bsum[t] : 0;
  s[t] = v; __syncthreads();
  for (int off = 1; off < 128; off <<= 1) {
    int xv = (t >= off) ? s[t - off] : 0;
    __syncthreads();
    s[t] += xv;
    __syncthreads();
  }
  if (t < nb) bsum[t] = s[t] - v;   // exclusive
}

__global__ void k_scan3(const int* __restrict__ deg, const int* __restrict__ bsum,
                        int N, int Et, int* __restrict__ row_ptr,
                        int* __restrict__ cursor, float* __restrict__ dinv)
{
  __shared__ int s[256];
  int t = threadIdx.x;
  int i = blockIdx.x * 256 + t;
  int v = (i < N) ? deg[i] : 0;
  s[t] = v; __syncthreads();
  for (int off = 1; off < 256; off <<= 1) {
    int xv = (t >= off) ? s[t - off] : 0;
    __syncthreads();
    s[t] += xv;
    __syncthreads();
  }
  if (i < N) {
    int excl = s[t] - v + bsum[blockIdx.x];
    row_ptr[i] = excl;
    cursor[i] = excl;
    dinv[i] = rsqrtf((float)v);    // deg >= 1 (self-loop)
  }
  if (i == 0) row_ptr[N] = Et;
}

__global__ void k_fill(const int* __restrict__ ei, int E, int N,
                       int* __restrict__ cursor, int* __restrict__ col_src)
{
  int e = blockIdx.x * blockDim.x + threadIdx.x;
  if (e >= E + N) return;
  int src, dst;
  if (e < E) { src = ei[e]; dst = ei[E + e]; }
  else       { src = e - E; dst = src; }
  int pos = atomicAdd(&cursor[dst], 1);
  col_src[pos] = src;
}

// ---------------- single-pass aggregation + gate + LayerNorm --------------------
// HALF-WAVE per node (lane owns 4 dims). 32-edge chunks; phase A computes exps ->
// wave-private LDS (+ zero-alpha sentinel at index cnt); phase B unrolled by 2 so
// each wave has 6 independent gathers in flight (2 nodes x {2x16B xh + 8B xg}).
__global__ __launch_bounds__(256) void k_agg(
    const unsigned short* __restrict__ xh, const unsigned short* __restrict__ xg,
    const float* __restrict__ a_s, const float* __restrict__ a_d,
    const int* __restrict__ row_ptr, const int* __restrict__ col_src,
    const float* __restrict__ dinv,
    const float* __restrict__ b_gat, const float* __restrict__ b_gcn,
    const float* __restrict__ W_gate, const float* __restrict__ b_gate,
    const float* __restrict__ gamma, const float* __restrict__ beta,
    float* __restrict__ out, int N)
{
  __shared__ float4 sh_al[8][33];
  __shared__ int    sh_src[8][33];
  __shared__ float  sh_cf[8][33];
  const int hw = threadIdx.x >> 5, lh = threadIdx.x & 31;
  const int n = blockIdx.x * 8 + hw;
  if (n >= N) return;
  const int start = row_ptr[n], end = row_ptr[n + 1];
  const float4 adn = ((const float4*)a_d)[n];

  float den0 = 0.f, den1 = 0.f, den2 = 0.f, den3 = 0.f;
  float g[4][4] = {};
  float c[4] = {};

  for (int base = start; base < end; base += 32) {
    const int cnt = min(32, end - base);
    if (lh < cnt) {
      int s = col_src[base + lh];
      float4 as4 = ((const float4*)a_s)[s];
      float e0 = as4.x + adn.x; e0 = (e0 >= 0.f) ? e0 : NEG_SLOPE * e0;
      float e1 = as4.y + adn.y; e1 = (e1 >= 0.f) ? e1 : NEG_SLOPE * e1;
      float e2 = as4.z + adn.z; e2 = (e2 >= 0.f) ? e2 : NEG_SLOPE * e2;
      float e3 = as4.w + adn.w; e3 = (e3 >= 0.f) ? e3 : NEG_SLOPE * e3;
      float x0 = __expf(e0), x1 = __expf(e1), x2 = __expf(e2), x3 = __expf(e3);
      den0 += x0; den1 += x1; den2 += x2; den3 += x3;
      sh_al[hw][lh] = make_float4(x0, x1, x2, x3);
      sh_src[hw][lh] = s;
      sh_cf[hw][lh] = dinv[s];
    }
    if (lh == 0) {   // sentinel (zero contribution, valid address)
      sh_al[hw][cnt] = make_float4(0.f, 0.f, 0.f, 0.f);
      sh_src[hw][cnt] = 0;
      sh_cf[hw][cnt] = 0.f;
    }
    for (int j = 0; j < cnt; j += 2) {
      float4 alA = sh_al[hw][j];     int sA = sh_src[hw][j];     float cfA = sh_cf[hw][j];
      float4 alB = sh_al[hw][j + 1]; int sB = sh_src[hw][j + 1]; float cfB = sh_cf[hw][j + 1];
      const unsigned short* rA = xh + ((size_t)sA << 9) + (lh << 4);
      const unsigned short* rB = xh + ((size_t)sB << 9) + (lh << 4);
      uint4 vA0 = *(const uint4*)rA;
      uint4 vA1 = *(const uint4*)(rA + 8);
      ushort4 gA = *(const ushort4*)(xg + ((size_t)sA << 7) + (lh << 2));
      uint4 vB0 = *(const uint4*)rB;
      uint4 vB1 = *(const uint4*)(rB + 8);
      ushort4 gB = *(const ushort4*)(xg + ((size_t)sB << 7) + (lh << 2));
      // edge A: dims 4lh..4lh+3 (v0 = dims 0,1; v1 = dims 2,3), heads in-register
      g[0][0] += alA.x * bflo(vA0.x); g[0][1] += alA.y * bfhi(vA0.x);
      g[0][2] += alA.z * bflo(vA0.y); g[0][3] += alA.w * bfhi(vA0.y);
      g[1][0] += alA.x * bflo(vA0.z); g[1][1] += alA.y * bfhi(vA0.z);
      g[1][2] += alA.z * bflo(vA0.w); g[1][3] += alA.w * bfhi(vA0.w);
      g[2][0] += alA.x * bflo(vA1.x); g[2][1] += alA.y * bfhi(vA1.x);
      g[2][2] += alA.z * bflo(vA1.y); g[2][3] += alA.w * bfhi(vA1.y);
      g[3][0] += alA.x * bflo(vA1.z); g[3][1] += alA.y * bfhi(vA1.z);
      g[3][2] += alA.z * bflo(vA1.w); g[3][3] += alA.w * bfhi(vA1.w);
      c[0] += cfA * bf2f(gA.x); c[1] += cfA * bf2f(gA.y);
      c[2] += cfA * bf2f(gA.z); c[3] += cfA * bf2f(gA.w);
      // edge B
      g[0][0] += alB.x * bflo(vB0.x); g[0][1] += alB.y * bfhi(vB0.x);
      g[0][2] += alB.z * bflo(vB0.y); g[0][3] += alB.w * bfhi(vB0.y);
      g[1][0] += alB.x * bflo(vB0.z); g[1][1] += alB.y * bfhi(vB0.z);
      g[1][2] += alB.z * bflo(vB0.w); g[1][3] += alB.w * bfhi(vB0.w);
      g[2][0] += alB.x * bflo(vB1.x); g[2][1] += alB.y * bfhi(vB1.x);
      g[2][2] += alB.z * bflo(vB1.y); g[2][3] += alB.w * bfhi(vB1.y);
      g[3][0] += alB.x * bflo(vB1.z); g[3][1] += alB.y * bfhi(vB1.z);
      g[3][2] += alB.z * bflo(vB1.w); g[3][3] += alB.w * bfhi(vB1.w);
      c[0] += cfB * bf2f(gB.x); c[1] += cfB * bf2f(gB.y);
      c[2] += cfB * bf2f(gB.z); c[3] += cfB * bf2f(gB.w);
    }
  }

  #pragma unroll
  for (int off = 16; off; off >>= 1) {
    den0 += __shfl_xor(den0, off); den1 += __shfl_xor(den1, off);
    den2 += __shfl_xor(den2, off); den3 += __shfl_xor(den3, off);
  }
  const float r0 = 1.f / den0, r1 = 1.f / den1, r2 = 1.f / den2, r3 = 1.f / den3;
  const float dn = dinv[n];
  float ga[4], gc[4];
  #pragma unroll
  for (int d = 0; d < 4; ++d) {
    ga[d] = g[d][0] * r0 + g[d][1] * r1 + g[d][2] * r2 + g[d][3] * r3;
    gc[d] = c[d] * dn;
  }

  // gate + residual + LayerNorm (lane lh owns dims 4lh..4lh+3)
  float4 bg = ((const float4*)b_gat)[lh];
  float4 bc = ((const float4*)b_gcn)[lh];
  ga[0] = ga[0] * 0.25f + bg.x; ga[1] = ga[1] * 0.25f + bg.y;
  ga[2] = ga[2] * 0.25f + bg.z; ga[3] = ga[3] * 0.25f + bg.w;
  gc[0] += bc.x; gc[1] += bc.y; gc[2] += bc.z; gc[3] += bc.w;
  float4 wa0 = ((const float4*)W_gate)[2 * lh];
  float4 wa1 = ((const float4*)W_gate)[2 * lh + 1];
  float4 wc0 = ((const float4*)W_gate)[64 + 2 * lh];
  float4 wc1 = ((const float4*)W_gate)[64 + 2 * lh + 1];
  float z0 = ga[0] * wa0.x + ga[1] * wa0.z + ga[2] * wa1.x + ga[3] * wa1.z
           + gc[0] * wc0.x + gc[1] * wc0.z + gc[2] * wc1.x + gc[3] * wc1.z;
  float z1 = ga[0] * wa0.y + ga[1] * wa0.w + ga[2] * wa1.y + ga[3] * wa1.w
           + gc[0] * wc0.y + gc[1] * wc0.w + gc[2] * wc1.y + gc[3] * wc1.w;
  #pragma unroll
  for (int off = 16; off; off >>= 1) { z0 += __shfl_xor(z0, off); z1 += __shfl_xor(z1, off); }
  z0 += b_gate[0]; z1 += b_gate[1];
  float mz = fmaxf(z0, z1);
  float ez0 = __expf(z0 - mz), ez1 = __expf(z1 - mz);
  float inv = 1.f / (ez0 + ez1);
  float w0 = ez0 * inv, w1 = ez1 * inv;
  float h0 = (1.f + w0) * ga[0] + w1 * gc[0];
  float h1 = (1.f + w0) * ga[1] + w1 * gc[1];
  float h2 = (1.f + w0) * ga[2] + w1 * gc[2];
  float h3 = (1.f + w0) * ga[3] + w1 * gc[3];
  float ssum = h0 + h1 + h2 + h3;
  #pragma unroll
  for (int off = 16; off; off >>= 1) ssum += __shfl_xor(ssum, off);
  float mu = ssum * (1.f / 128.f);
  float v0 = h0 - mu, v1 = h1 - mu, v2 = h2 - mu, v3 = h3 - mu;
  float vsum = v0 * v0 + v1 * v1 + v2 * v2 + v3 * v3;
  #pragma unroll
  for (int off = 16; off; off >>= 1) vsum += __shfl_xor(vsum, off);
  float rstd = rsqrtf(vsum * (1.f / 128.f) + LN_EPS);
  float4 gm = ((const float4*)gamma)[lh];
  float4 bt = ((const float4*)beta)[lh];
  float4 o;
  o.x = v0 * rstd * gm.x + bt.x;
  o.y = v1 * rstd * gm.y + bt.y;
  o.z = v2 * rstd * gm.z + bt.z;
  o.w = v3 * rstd * gm.w + bt.w;
  ((float4*)out)[(size_t)n * 32 + lh] = o;
}

extern "C" void kernel_launch(void* const* d_in, const int* in_sizes, int n_in,
                              void* d_out, int out_size, void* d_ws, size_t ws_size,
                              hipStream_t stream)
{
  const float* x       = (const float*)d_in[0];
  const int*   ei      = (const int*)d_in[1];
  const float* Wgat    = (const float*)d_in[2];
  const float* att_src = (const float*)d_in[3];
  const float* att_dst = (const float*)d_in[4];
  const float* b_gat   = (const float*)d_in[5];
  const float* Wgcn    = (const float*)d_in[6];
  const float* b_gcn   = (const float*)d_in[7];
  const float* W_gate  = (const float*)d_in[8];
  const float* b_gate  = (const float*)d_in[9];
  const float* gamma   = (const float*)d_in[10];
  const float* beta    = (const float*)d_in[11];
  float* out = (float*)d_out;

  const int N  = in_sizes[0] / D;   // 30000
  const int E  = in_sizes[1] / 2;   // 480000
  const int Et = E + N;

  char* p = (char*)d_ws;
  unsigned short* xh = (unsigned short*)p; p += (size_t)N * NH * D * 2;  // [n][d][h]
  unsigned short* xg = (unsigned short*)p; p += (size_t)N * D * 2;       // [n][d]
  unsigned short* Wt = (unsigned short*)p; p += (size_t)640 * D * 2;
  float* a_s     = (float*)p; p += (size_t)N * NH * 4;
  float* a_d     = (float*)p; p += (size_t)N * NH * 4;
  float* dinv    = (float*)p; p += (size_t)N * 4;
  int* deg       = (int*)p;   p += (size_t)N * 4;
  int* row_ptr   = (int*)p;   p += (size_t)(N + 1) * 4;
  int* cursor    = (int*)p;   p += (size_t)N * 4;
  int* col_src   = (int*)p;   p += (size_t)Et * 4;
  int* bsum      = (int*)p;   p += 1024;

  hipMemsetAsync(deg, 0, (size_t)N * 4, stream);

  k_prep_w<<<640, 128, 0, stream>>>(Wgat, Wgcn, Wt);
  dim3 gg((N + 127) / 128, 10);
  k_gemm_mfma<<<gg, 256, 0, stream>>>(x, Wt, xh, xg, N);
  k_att<<<(N + 3) / 4, 256, 0, stream>>>(xh, att_src, att_dst, a_s, a_d, N);
  k_deg<<<(Et + 255) / 256, 256, 0, stream>>>(ei, E, N, deg);
  int nb = (N + 255) / 256;
  k_scan1<<<nb, 256, 0, stream>>>(deg, N, bsum);
  k_scan2<<<1, 128, 0, stream>>>(bsum, nb);
  k_scan3<<<nb, 256, 0, stream>>>(deg, bsum, N, Et, row_ptr, cursor, dinv);
  k_fill<<<(Et + 255) / 256, 256, 0, stream>>>(ei, E, N, cursor, col_src);
  k_agg<<<(N + 7) / 8, 256, 0, stream>>>(xh, xg, a_s, a_d, row_ptr, col_src, dinv,
                                          b_gat, b_gcn, W_gate, b_gate, gamma, beta,
                                          out, N);
  (void)n_in; (void)out_size; (void)ws_size;
}

// Round 6
// 178.866 us; speedup vs baseline: 1.2747x; 1.2747x over previous
//
#include <hip/hip_runtime.h>
#include <hip/hip_bf16.h>

#define D 128
#define NH 4
#define NEG_SLOPE 0.2f
#define LN_EPS 1e-5f

typedef __attribute__((ext_vector_type(4))) float f32x4;
typedef __attribute__((ext_vector_type(8))) short bf16x8;

__device__ __forceinline__ float bf2f(unsigned short u) {
  union { unsigned int i; float f; } c; c.i = ((unsigned int)u) << 16; return c.f;
}
__device__ __forceinline__ unsigned short f2bf(float f) {
  union { float f; unsigned int i; } c; c.f = f;
  unsigned int r = c.i + 0x7FFFu + ((c.i >> 16) & 1u);  // RNE
  return (unsigned short)(r >> 16);
}

// ---------------- weight prep ---------------------------------------------------
// Wt2g[c][k] = W_gat[h=k>>7][k&127][c]  (c in [0,128), k in [0,512))  bf16
// Wt2c[c][k] = W_gcn[k][c]              (k in [0,128))                bf16
__global__ __launch_bounds__(128) void k_prep_w2(
    const float* __restrict__ Wgat, const float* __restrict__ Wgcn,
    unsigned short* __restrict__ Wt2g, unsigned short* __restrict__ Wt2c)
{
  int c = blockIdx.x, t = threadIdx.x;
  if (c < 128) {
    #pragma unroll
    for (int i = 0; i < 4; ++i) {
      int k = t + i * 128;
      int h = k >> 7, kk = k & 127;
      Wt2g[c * 512 + k] = f2bf(Wgat[((size_t)h * D + kk) * D + c]);
    }
  } else {
    int cc = c - 128;
    Wt2c[cc * 128 + t] = f2bf(Wgcn[(size_t)t * D + cc]);
  }
}

// wtil_s[h*128+k] = sum_f W_gat[h][k][f] * att_src[h][f]; wtil_d same with att_dst
__global__ __launch_bounds__(128) void k_wtilde(
    const float* __restrict__ Wgat,
    const float* __restrict__ att_src, const float* __restrict__ att_dst,
    float* __restrict__ wtil_s, float* __restrict__ wtil_d)
{
  int h = blockIdx.x >> 1, which = blockIdx.x & 1;
  int k = threadIdx.x;
  const float* av = (which ? att_dst : att_src) + h * D;
  const float* Wrow = Wgat + ((size_t)h * D + k) * D;
  float s = 0.f;
  for (int f = 0; f < D; ++f) s += Wrow[f] * av[f];
  (which ? wtil_d : wtil_s)[h * D + k] = s;
}

// ---------------- x -> bf16 copy + attention dots a_s, a_d ----------------------
__global__ __launch_bounds__(256) void k_xb(
    const float* __restrict__ x,
    const float* __restrict__ wtil_s, const float* __restrict__ wtil_d,
    unsigned short* __restrict__ xb, float* __restrict__ a_s, float* __restrict__ a_d,
    int N)
{
  const int w = threadIdx.x >> 6, l = threadIdx.x & 63;
  const int n = blockIdx.x * 4 + w;
  if (n >= N) return;
  float2 xv = ((const float2*)(x + (size_t)n * D))[l];
  ushort2 p; p.x = f2bf(xv.x); p.y = f2bf(xv.y);
  *(ushort2*)(xb + (size_t)n * D + 2 * l) = p;
  float s0 = xv.x * wtil_s[2*l]       + xv.y * wtil_s[2*l+1];
  float s1 = xv.x * wtil_s[D+2*l]     + xv.y * wtil_s[D+2*l+1];
  float s2 = xv.x * wtil_s[2*D+2*l]   + xv.y * wtil_s[2*D+2*l+1];
  float s3 = xv.x * wtil_s[3*D+2*l]   + xv.y * wtil_s[3*D+2*l+1];
  float d0 = xv.x * wtil_d[2*l]       + xv.y * wtil_d[2*l+1];
  float d1 = xv.x * wtil_d[D+2*l]     + xv.y * wtil_d[D+2*l+1];
  float d2 = xv.x * wtil_d[2*D+2*l]   + xv.y * wtil_d[2*D+2*l+1];
  float d3 = xv.x * wtil_d[3*D+2*l]   + xv.y * wtil_d[3*D+2*l+1];
  #pragma unroll
  for (int off = 32; off; off >>= 1) {
    s0 += __shfl_xor(s0, off); s1 += __shfl_xor(s1, off);
    s2 += __shfl_xor(s2, off); s3 += __shfl_xor(s3, off);
    d0 += __shfl_xor(d0, off); d1 += __shfl_xor(d1, off);
    d2 += __shfl_xor(d2, off); d3 += __shfl_xor(d3, off);
  }
  if (l == 0) {
    ((float4*)a_s)[n] = make_float4(s0, s1, s2, s3);
    ((float4*)a_d)[n] = make_float4(d0, d1, d2, d3);
  }
}

// ---------------- CSR build ----------------------------------------------------
__global__ void k_deg(const int* __restrict__ ei, int E, int N, int* __restrict__ deg)
{
  int e = blockIdx.x * blockDim.x + threadIdx.x;
  if (e >= E + N) return;
  int dst = (e < E) ? ei[E + e] : (e - E);
  atomicAdd(&deg[dst], 1);
}

__global__ void k_scan1(const int* __restrict__ deg, int N, int* __restrict__ bsum)
{
  __shared__ int s[256];
  int t = threadIdx.x;
  int i = blockIdx.x * 256 + t;
  s[t] = (i < N) ? deg[i] : 0;
  __syncthreads();
  for (int off = 128; off; off >>= 1) {
    if (t < off) s[t] += s[t + off];
    __syncthreads();
  }
  if (t == 0) bsum[blockIdx.x] = s[0];
}

__global__ void k_scan2(int* __restrict__ bsum, int nb)
{
  __shared__ int s[128];
  int t = threadIdx.x;
  int v = (t < nb) ? bsum[t] : 0;
  s[t] = v; __syncthreads();
  for (int off = 1; off < 128; off <<= 1) {
    int xv = (t >= off) ? s[t - off] : 0;
    __syncthreads();
    s[t] += xv;
    __syncthreads();
  }
  if (t < nb) bsum[t] = s[t] - v;   // exclusive
}

__global__ void k_scan3(const int* __restrict__ deg, const int* __restrict__ bsum,
                        int N, int Et, int* __restrict__ row_ptr,
                        int* __restrict__ cursor, float* __restrict__ dinv)
{
  __shared__ int s[256];
  int t = threadIdx.x;
  int i = blockIdx.x * 256 + t;
  int v = (i < N) ? deg[i] : 0;
  s[t] = v; __syncthreads();
  for (int off = 1; off < 256; off <<= 1) {
    int xv = (t >= off) ? s[t - off] : 0;
    __syncthreads();
    s[t] += xv;
    __syncthreads();
  }
  if (i < N) {
    int excl = s[t] - v + bsum[blockIdx.x];
    row_ptr[i] = excl;
    cursor[i] = excl;
    dinv[i] = rsqrtf((float)v);    // deg >= 1 (self-loop)
  }
  if (i == 0) row_ptr[N] = Et;
}

__global__ void k_fill(const int* __restrict__ ei, int E, int N,
                       int* __restrict__ cursor, int* __restrict__ col_src)
{
  int e = blockIdx.x * blockDim.x + threadIdx.x;
  if (e >= E + N) return;
  int src, dst;
  if (e < E) { src = ei[e]; dst = ei[E + e]; }
  else       { src = e - E; dst = src; }
  int pos = atomicAdd(&cursor[dst], 1);
  col_src[pos] = src;
}

// ---------------- x-domain aggregation ------------------------------------------
// Half-wave per node (lane owns 4 dims of 128). Per edge gather ONLY xb (256B).
// Accumulate 4 head-weighted sums + 1 coef-weighted sum; normalize at end; write
// UV[n][640] bf16 (U: k=h*128+d, V: k=512+d).
__global__ __launch_bounds__(256) void k_agg2(
    const unsigned short* __restrict__ xb,
    const float* __restrict__ a_s, const float* __restrict__ a_d,
    const int* __restrict__ row_ptr, const int* __restrict__ col_src,
    const float* __restrict__ dinv,
    unsigned short* __restrict__ UV, int N)
{
  __shared__ float4 sh_al[8][33];
  __shared__ int    sh_src[8][33];
  __shared__ float  sh_cf[8][33];
  const int hw = threadIdx.x >> 5, lh = threadIdx.x & 31;
  const int n = blockIdx.x * 8 + hw;
  if (n >= N) return;
  const int start = row_ptr[n], end = row_ptr[n + 1];
  const float4 adn = ((const float4*)a_d)[n];

  float den0 = 0.f, den1 = 0.f, den2 = 0.f, den3 = 0.f;
  float ug[4][4] = {};
  float vg[4] = {};

  for (int base = start; base < end; base += 32) {
    const int cnt = min(32, end - base);
    if (lh < cnt) {
      int s = col_src[base + lh];
      float4 as4 = ((const float4*)a_s)[s];
      float e0 = as4.x + adn.x; e0 = (e0 >= 0.f) ? e0 : NEG_SLOPE * e0;
      float e1 = as4.y + adn.y; e1 = (e1 >= 0.f) ? e1 : NEG_SLOPE * e1;
      float e2 = as4.z + adn.z; e2 = (e2 >= 0.f) ? e2 : NEG_SLOPE * e2;
      float e3 = as4.w + adn.w; e3 = (e3 >= 0.f) ? e3 : NEG_SLOPE * e3;
      float x0 = __expf(e0), x1 = __expf(e1), x2 = __expf(e2), x3 = __expf(e3);
      den0 += x0; den1 += x1; den2 += x2; den3 += x3;
      sh_al[hw][lh] = make_float4(x0, x1, x2, x3);
      sh_src[hw][lh] = s;
      sh_cf[hw][lh] = dinv[s];
    }
    if (lh == 0) {   // sentinel
      sh_al[hw][cnt] = make_float4(0.f, 0.f, 0.f, 0.f);
      sh_src[hw][cnt] = 0;
      sh_cf[hw][cnt] = 0.f;
    }
    for (int j = 0; j < cnt; j += 2) {
      float4 alA = sh_al[hw][j];     int sA = sh_src[hw][j];     float cfA = sh_cf[hw][j];
      float4 alB = sh_al[hw][j + 1]; int sB = sh_src[hw][j + 1]; float cfB = sh_cf[hw][j + 1];
      ushort4 xA = *(const ushort4*)(xb + ((size_t)sA << 7) + (lh << 2));
      ushort4 xB = *(const ushort4*)(xb + ((size_t)sB << 7) + (lh << 2));
      float fa[4] = {bf2f(xA.x), bf2f(xA.y), bf2f(xA.z), bf2f(xA.w)};
      float fb[4] = {bf2f(xB.x), bf2f(xB.y), bf2f(xB.z), bf2f(xB.w)};
      float aA[4] = {alA.x, alA.y, alA.z, alA.w};
      float aB[4] = {alB.x, alB.y, alB.z, alB.w};
      #pragma unroll
      for (int h = 0; h < 4; ++h)
        #pragma unroll
        for (int d = 0; d < 4; ++d)
          ug[h][d] += aA[h] * fa[d] + aB[h] * fb[d];
      #pragma unroll
      for (int d = 0; d < 4; ++d)
        vg[d] += cfA * fa[d] + cfB * fb[d];
    }
  }

  #pragma unroll
  for (int off = 16; off; off >>= 1) {
    den0 += __shfl_xor(den0, off); den1 += __shfl_xor(den1, off);
    den2 += __shfl_xor(den2, off); den3 += __shfl_xor(den3, off);
  }
  const float r[4] = {1.f / den0, 1.f / den1, 1.f / den2, 1.f / den3};
  const float dn = dinv[n];
  unsigned short* uvp = UV + (size_t)n * 640;
  #pragma unroll
  for (int h = 0; h < 4; ++h) {
    ushort4 u;
    u.x = f2bf(ug[h][0] * r[h]); u.y = f2bf(ug[h][1] * r[h]);
    u.z = f2bf(ug[h][2] * r[h]); u.w = f2bf(ug[h][3] * r[h]);
    *(ushort4*)(uvp + h * 128 + 4 * lh) = u;
  }
  ushort4 v4;
  v4.x = f2bf(vg[0] * dn); v4.y = f2bf(vg[1] * dn);
  v4.z = f2bf(vg[2] * dn); v4.w = f2bf(vg[3] * dn);
  *(ushort4*)(uvp + 512 + 4 * lh) = v4;
}

// ---------------- MFMA GEMM 2: [U|V] @ [Wstack | Wgcn] -> acc_g, acc_c (bf16) ---
// BM=64 rows, 256 cols (gat 128 via K=512, gcn 128 via K=128). B streamed from L2.
__global__ __launch_bounds__(256) void k_gemm2(
    const unsigned short* __restrict__ UV,
    const unsigned short* __restrict__ Wt2g, const unsigned short* __restrict__ Wt2c,
    unsigned short* __restrict__ acc_g, unsigned short* __restrict__ acc_c, int N)
{
  __shared__ unsigned short Ulds[64 * 640];   // [row][k], 16B-block kb ^= row&7
  const int t = threadIdx.x;
  const int m0 = blockIdx.x * 64;

  #pragma unroll
  for (int i = 0; i < 20; ++i) {
    int g = i * 256 + t;        // 16B-block index, 5120 total
    int row = g / 80, kb = g - row * 80;
    int gr = m0 + row;
    uint4 v = make_uint4(0u, 0u, 0u, 0u);
    if (gr < N) v = *(const uint4*)(UV + (size_t)gr * 640 + kb * 8);
    *(uint4*)&Ulds[row * 640 + ((kb ^ (row & 7)) << 3)] = v;
  }
  __syncthreads();

  const int w = t >> 6, l = t & 63;
  const int lrow = l & 15, lk = l >> 4;
  const int arow = w * 16 + lrow;

  f32x4 acc[16];
  #pragma unroll
  for (int i = 0; i < 16; ++i) acc[i] = (f32x4){0.f, 0.f, 0.f, 0.f};

  // gat: K = 512 (UV blocks 0..63)
  #pragma unroll
  for (int ks = 0; ks < 16; ++ks) {
    int kb = ks * 4 + lk;
    bf16x8 a = *(const bf16x8*)&Ulds[arow * 640 + ((kb ^ (arow & 7)) << 3)];
    #pragma unroll
    for (int ct = 0; ct < 8; ++ct) {
      bf16x8 b = *(const bf16x8*)&Wt2g[(size_t)(ct * 16 + lrow) * 512 + ks * 32 + lk * 8];
      acc[ct] = __builtin_amdgcn_mfma_f32_16x16x32_bf16(a, b, acc[ct], 0, 0, 0);
    }
  }
  // gcn: K = 128 -> V lives at short offset 512 = 16B-block 64 (BUGFIX: was 32)
  #pragma unroll
  for (int ks = 0; ks < 4; ++ks) {
    int kb = 64 + ks * 4 + lk;
    bf16x8 a = *(const bf16x8*)&Ulds[arow * 640 + ((kb ^ (arow & 7)) << 3)];
    #pragma unroll
    for (int ct = 0; ct < 8; ++ct) {
      bf16x8 b = *(const bf16x8*)&Wt2c[(size_t)(ct * 16 + lrow) * 128 + ks * 32 + lk * 8];
      acc[8 + ct] = __builtin_amdgcn_mfma_f32_16x16x32_bf16(a, b, acc[8 + ct], 0, 0, 0);
    }
  }

  #pragma unroll
  for (int i = 0; i < 16; ++i) {
    int col = (i & 7) * 16 + lrow;
    unsigned short* dst = (i < 8) ? acc_g : acc_c;
    #pragma unroll
    for (int j = 0; j < 4; ++j) {
      int r = m0 + w * 16 + lk * 4 + j;
      if (r >= N) continue;
      dst[(size_t)r * 128 + col] = f2bf(acc[i][j]);
    }
  }
}

// ---------------- gate + residual + LayerNorm ----------------------------------
__global__ __launch_bounds__(256) void k_final(
    const unsigned short* __restrict__ acc_g, const unsigned short* __restrict__ acc_c,
    const float* __restrict__ b_gat, const float* __restrict__ b_gcn,
    const float* __restrict__ W_gate, const float* __restrict__ b_gate,
    const float* __restrict__ gamma, const float* __restrict__ beta,
    float* __restrict__ out, int N)
{
  int n = blockIdx.x * 4 + (threadIdx.x >> 6);
  if (n >= N) return;
  int l = threadIdx.x & 63;
  ushort2 gau = *(const ushort2*)(acc_g + (size_t)n * 128 + 2 * l);
  ushort2 gcu = *(const ushort2*)(acc_c + (size_t)n * 128 + 2 * l);
  float2 ga = make_float2(bf2f(gau.x), bf2f(gau.y));
  float2 gc = make_float2(bf2f(gcu.x), bf2f(gcu.y));
  float2 bg = ((const float2*)b_gat)[l];
  float2 bc = ((const float2*)b_gcn)[l];
  float g0x = ga.x * 0.25f + bg.x, g0y = ga.y * 0.25f + bg.y;
  float c0x = gc.x + bc.x,         c0y = gc.y + bc.y;
  float4 wa = ((const float4*)W_gate)[l];        // rows 2l, 2l+1
  float4 wc = ((const float4*)W_gate)[64 + l];   // rows 128+2l, 128+2l+1
  float z0 = g0x * wa.x + g0y * wa.z + c0x * wc.x + c0y * wc.z;
  float z1 = g0x * wa.y + g0y * wa.w + c0x * wc.y + c0y * wc.w;
  #pragma unroll
  for (int off = 32; off; off >>= 1) { z0 += __shfl_xor(z0, off); z1 += __shfl_xor(z1, off); }
  z0 += b_gate[0]; z1 += b_gate[1];
  float mz = fmaxf(z0, z1);
  float ez0 = __expf(z0 - mz), ez1 = __expf(z1 - mz);
  float inv = 1.f / (ez0 + ez1);
  float w0 = ez0 * inv, w1 = ez1 * inv;
  float hx = (1.f + w0) * g0x + w1 * c0x;   // fused + gat_out
  float hy = (1.f + w0) * g0y + w1 * c0y;
  float ssum = hx + hy;
  #pragma unroll
  for (int off = 32; off; off >>= 1) ssum += __shfl_xor(ssum, off);
  float mu = ssum * (1.f / 128.f);
  float vx = hx - mu, vy = hy - mu;
  float vsum = vx * vx + vy * vy;
  #pragma unroll
  for (int off = 32; off; off >>= 1) vsum += __shfl_xor(vsum, off);
  float rstd = rsqrtf(vsum * (1.f / 128.f) + LN_EPS);
  float2 gm = ((const float2*)gamma)[l];
  float2 bt = ((const float2*)beta)[l];
  float2 o;
  o.x = vx * rstd * gm.x + bt.x;
  o.y = vy * rstd * gm.y + bt.y;
  ((float2*)out)[(size_t)n * 64 + l] = o;
}

extern "C" void kernel_launch(void* const* d_in, const int* in_sizes, int n_in,
                              void* d_out, int out_size, void* d_ws, size_t ws_size,
                              hipStream_t stream)
{
  const float* x       = (const float*)d_in[0];
  const int*   ei      = (const int*)d_in[1];
  const float* Wgat    = (const float*)d_in[2];
  const float* att_src = (const float*)d_in[3];
  const float* att_dst = (const float*)d_in[4];
  const float* b_gat   = (const float*)d_in[5];
  const float* Wgcn    = (const float*)d_in[6];
  const float* b_gcn   = (const float*)d_in[7];
  const float* W_gate  = (const float*)d_in[8];
  const float* b_gate  = (const float*)d_in[9];
  const float* gamma   = (const float*)d_in[10];
  const float* beta    = (const float*)d_in[11];
  float* out = (float*)d_out;

  const int N  = in_sizes[0] / D;   // 30000
  const int E  = in_sizes[1] / 2;   // 480000
  const int Et = E + N;

  char* p = (char*)d_ws;
  unsigned short* xb   = (unsigned short*)p; p += (size_t)N * D * 2;        // 7.7MB
  unsigned short* UV   = (unsigned short*)p; p += (size_t)N * 640 * 2;      // 38.4MB
  unsigned short* Wt2g = (unsigned short*)p; p += (size_t)128 * 512 * 2;
  unsigned short* Wt2c = (unsigned short*)p; p += (size_t)128 * 128 * 2;
  unsigned short* accg = (unsigned short*)p; p += (size_t)N * D * 2;        // 7.7MB
  unsigned short* accc = (unsigned short*)p; p += (size_t)N * D * 2;        // 7.7MB
  float* wtil_s  = (float*)p; p += 512 * 4;
  float* wtil_d  = (float*)p; p += 512 * 4;
  float* a_s     = (float*)p; p += (size_t)N * NH * 4;
  float* a_d     = (float*)p; p += (size_t)N * NH * 4;
  float* dinv    = (float*)p; p += (size_t)N * 4;
  int* deg       = (int*)p;   p += (size_t)N * 4;
  int* row_ptr   = (int*)p;   p += (size_t)(N + 1) * 4;
  int* cursor    = (int*)p;   p += (size_t)N * 4;
  int* col_src   = (int*)p;   p += (size_t)Et * 4;
  int* bsum      = (int*)p;   p += 1024;

  hipMemsetAsync(deg, 0, (size_t)N * 4, stream);

  k_prep_w2<<<256, 128, 0, stream>>>(Wgat, Wgcn, Wt2g, Wt2c);
  k_wtilde<<<8, 128, 0, stream>>>(Wgat, att_src, att_dst, wtil_s, wtil_d);
  k_xb<<<(N + 3) / 4, 256, 0, stream>>>(x, wtil_s, wtil_d, xb, a_s, a_d, N);
  k_deg<<<(Et + 255) / 256, 256, 0, stream>>>(ei, E, N, deg);
  int nb = (N + 255) / 256;
  k_scan1<<<nb, 256, 0, stream>>>(deg, N, bsum);
  k_scan2<<<1, 128, 0, stream>>>(bsum, nb);
  k_scan3<<<nb, 256, 0, stream>>>(deg, bsum, N, Et, row_ptr, cursor, dinv);
  k_fill<<<(Et + 255) / 256, 256, 0, stream>>>(ei, E, N, cursor, col_src);
  k_agg2<<<(N + 7) / 8, 256, 0, stream>>>(xb, a_s, a_d, row_ptr, col_src, dinv, UV, N);
  k_gemm2<<<(N + 63) / 64, 256, 0, stream>>>(UV, Wt2g, Wt2c, accg, accc, N);
  k_final<<<(N + 3) / 4, 256, 0, stream>>>(accg, accc, b_gat, b_gcn,
                                            W_gate, b_gate, gamma, beta, out, N);
  (void)n_in; (void)out_size; (void)ws_size;
}

// Round 7
// 151.577 us; speedup vs baseline: 1.5042x; 1.1800x over previous
//
#include <hip/hip_runtime.h>
#include <hip/hip_bf16.h>

#define D 128
#define NH 4
#define NEG_SLOPE 0.2f
#define LN_EPS 1e-5f

typedef __attribute__((ext_vector_type(4))) float f32x4;
typedef __attribute__((ext_vector_type(8))) short bf16x8;

__device__ __forceinline__ float bf2f(unsigned short u) {
  union { unsigned int i; float f; } c; c.i = ((unsigned int)u) << 16; return c.f;
}
__device__ __forceinline__ unsigned short f2bf(float f) {
  union { float f; unsigned int i; } c; c.f = f;
  unsigned int r = c.i + 0x7FFFu + ((c.i >> 16) & 1u);  // RNE
  return (unsigned short)(r >> 16);
}

// ---------------- weight prep ---------------------------------------------------
// Wt2g[c][k] = W_gat[h=k>>7][k&127][c]  (c in [0,128), k in [0,512))  bf16
// Wt2c[c][k] = W_gcn[k][c]              (k in [0,128))                bf16
__global__ __launch_bounds__(128) void k_prep_w2(
    const float* __restrict__ Wgat, const float* __restrict__ Wgcn,
    unsigned short* __restrict__ Wt2g, unsigned short* __restrict__ Wt2c)
{
  int c = blockIdx.x, t = threadIdx.x;
  if (c < 128) {
    #pragma unroll
    for (int i = 0; i < 4; ++i) {
      int k = t + i * 128;
      int h = k >> 7, kk = k & 127;
      Wt2g[c * 512 + k] = f2bf(Wgat[((size_t)h * D + kk) * D + c]);
    }
  } else {
    int cc = c - 128;
    Wt2c[cc * 128 + t] = f2bf(Wgcn[(size_t)t * D + cc]);
  }
}

// wtil_s[h*128+k] = sum_f W_gat[h][k][f] * att_src[h][f]; wtil_d same with att_dst
__global__ __launch_bounds__(128) void k_wtilde(
    const float* __restrict__ Wgat,
    const float* __restrict__ att_src, const float* __restrict__ att_dst,
    float* __restrict__ wtil_s, float* __restrict__ wtil_d)
{
  int h = blockIdx.x >> 1, which = blockIdx.x & 1;
  int k = threadIdx.x;
  const float* av = (which ? att_dst : att_src) + h * D;
  const float* Wrow = Wgat + ((size_t)h * D + k) * D;
  float s = 0.f;
  for (int f = 0; f < D; ++f) s += Wrow[f] * av[f];
  (which ? wtil_d : wtil_s)[h * D + k] = s;
}

// ---------------- x -> bf16 copy + attention dots a_s, a_d ----------------------
__global__ __launch_bounds__(256) void k_xb(
    const float* __restrict__ x,
    const float* __restrict__ wtil_s, const float* __restrict__ wtil_d,
    unsigned short* __restrict__ xb, float* __restrict__ a_s, float* __restrict__ a_d,
    int N)
{
  const int w = threadIdx.x >> 6, l = threadIdx.x & 63;
  const int n = blockIdx.x * 4 + w;
  if (n >= N) return;
  float2 xv = ((const float2*)(x + (size_t)n * D))[l];
  ushort2 p; p.x = f2bf(xv.x); p.y = f2bf(xv.y);
  *(ushort2*)(xb + (size_t)n * D + 2 * l) = p;
  float s0 = xv.x * wtil_s[2*l]       + xv.y * wtil_s[2*l+1];
  float s1 = xv.x * wtil_s[D+2*l]     + xv.y * wtil_s[D+2*l+1];
  float s2 = xv.x * wtil_s[2*D+2*l]   + xv.y * wtil_s[2*D+2*l+1];
  float s3 = xv.x * wtil_s[3*D+2*l]   + xv.y * wtil_s[3*D+2*l+1];
  float d0 = xv.x * wtil_d[2*l]       + xv.y * wtil_d[2*l+1];
  float d1 = xv.x * wtil_d[D+2*l]     + xv.y * wtil_d[D+2*l+1];
  float d2 = xv.x * wtil_d[2*D+2*l]   + xv.y * wtil_d[2*D+2*l+1];
  float d3 = xv.x * wtil_d[3*D+2*l]   + xv.y * wtil_d[3*D+2*l+1];
  #pragma unroll
  for (int off = 32; off; off >>= 1) {
    s0 += __shfl_xor(s0, off); s1 += __shfl_xor(s1, off);
    s2 += __shfl_xor(s2, off); s3 += __shfl_xor(s3, off);
    d0 += __shfl_xor(d0, off); d1 += __shfl_xor(d1, off);
    d2 += __shfl_xor(d2, off); d3 += __shfl_xor(d3, off);
  }
  if (l == 0) {
    ((float4*)a_s)[n] = make_float4(s0, s1, s2, s3);
    ((float4*)a_d)[n] = make_float4(d0, d1, d2, d3);
  }
}

// ---------------- CSR build ----------------------------------------------------
__global__ void k_deg(const int* __restrict__ ei, int E, int N, int* __restrict__ deg)
{
  int e = blockIdx.x * blockDim.x + threadIdx.x;
  if (e >= E + N) return;
  int dst = (e < E) ? ei[E + e] : (e - E);
  atomicAdd(&deg[dst], 1);
}

__global__ void k_scan1(const int* __restrict__ deg, int N, int* __restrict__ bsum)
{
  __shared__ int s[256];
  int t = threadIdx.x;
  int i = blockIdx.x * 256 + t;
  s[t] = (i < N) ? deg[i] : 0;
  __syncthreads();
  for (int off = 128; off; off >>= 1) {
    if (t < off) s[t] += s[t + off];
    __syncthreads();
  }
  if (t == 0) bsum[blockIdx.x] = s[0];
}

__global__ void k_scan2(int* __restrict__ bsum, int nb)
{
  __shared__ int s[128];
  int t = threadIdx.x;
  int v = (t < nb) ? bsum[t] : 0;
  s[t] = v; __syncthreads();
  for (int off = 1; off < 128; off <<= 1) {
    int xv = (t >= off) ? s[t - off] : 0;
    __syncthreads();
    s[t] += xv;
    __syncthreads();
  }
  if (t < nb) bsum[t] = s[t] - v;   // exclusive
}

__global__ void k_scan3(const int* __restrict__ deg, const int* __restrict__ bsum,
                        int N, int Et, int* __restrict__ row_ptr,
                        int* __restrict__ cursor, float* __restrict__ dinv)
{
  __shared__ int s[256];
  int t = threadIdx.x;
  int i = blockIdx.x * 256 + t;
  int v = (i < N) ? deg[i] : 0;
  s[t] = v; __syncthreads();
  for (int off = 1; off < 256; off <<= 1) {
    int xv = (t >= off) ? s[t - off] : 0;
    __syncthreads();
    s[t] += xv;
    __syncthreads();
  }
  if (i < N) {
    int excl = s[t] - v + bsum[blockIdx.x];
    row_ptr[i] = excl;
    cursor[i] = excl;
    dinv[i] = rsqrtf((float)v);    // deg >= 1 (self-loop)
  }
  if (i == 0) row_ptr[N] = Et;
}

__global__ void k_fill(const int* __restrict__ ei, int E, int N,
                       int* __restrict__ cursor, int* __restrict__ col_src)
{
  int e = blockIdx.x * blockDim.x + threadIdx.x;
  if (e >= E + N) return;
  int src, dst;
  if (e < E) { src = ei[e]; dst = ei[E + e]; }
  else       { src = e - E; dst = src; }
  int pos = atomicAdd(&cursor[dst], 1);
  col_src[pos] = src;
}

// ---------------- x-domain aggregation ------------------------------------------
// Half-wave per node (lane owns 4 dims of 128). Per edge gather ONLY xb (256B).
// Accumulate 4 head-weighted sums + 1 coef-weighted sum; normalize at end; write
// UV[n][640] bf16 (U: k=h*128+d, V: k=512+d).
__global__ __launch_bounds__(256) void k_agg2(
    const unsigned short* __restrict__ xb,
    const float* __restrict__ a_s, const float* __restrict__ a_d,
    const int* __restrict__ row_ptr, const int* __restrict__ col_src,
    const float* __restrict__ dinv,
    unsigned short* __restrict__ UV, int N)
{
  __shared__ float4 sh_al[8][33];
  __shared__ int    sh_src[8][33];
  __shared__ float  sh_cf[8][33];
  const int hw = threadIdx.x >> 5, lh = threadIdx.x & 31;
  const int n = blockIdx.x * 8 + hw;
  if (n >= N) return;
  const int start = row_ptr[n], end = row_ptr[n + 1];
  const float4 adn = ((const float4*)a_d)[n];

  float den0 = 0.f, den1 = 0.f, den2 = 0.f, den3 = 0.f;
  float ug[4][4] = {};
  float vg[4] = {};

  for (int base = start; base < end; base += 32) {
    const int cnt = min(32, end - base);
    if (lh < cnt) {
      int s = col_src[base + lh];
      float4 as4 = ((const float4*)a_s)[s];
      float e0 = as4.x + adn.x; e0 = (e0 >= 0.f) ? e0 : NEG_SLOPE * e0;
      float e1 = as4.y + adn.y; e1 = (e1 >= 0.f) ? e1 : NEG_SLOPE * e1;
      float e2 = as4.z + adn.z; e2 = (e2 >= 0.f) ? e2 : NEG_SLOPE * e2;
      float e3 = as4.w + adn.w; e3 = (e3 >= 0.f) ? e3 : NEG_SLOPE * e3;
      float x0 = __expf(e0), x1 = __expf(e1), x2 = __expf(e2), x3 = __expf(e3);
      den0 += x0; den1 += x1; den2 += x2; den3 += x3;
      sh_al[hw][lh] = make_float4(x0, x1, x2, x3);
      sh_src[hw][lh] = s;
      sh_cf[hw][lh] = dinv[s];
    }
    if (lh == 0) {   // sentinel
      sh_al[hw][cnt] = make_float4(0.f, 0.f, 0.f, 0.f);
      sh_src[hw][cnt] = 0;
      sh_cf[hw][cnt] = 0.f;
    }
    for (int j = 0; j < cnt; j += 2) {
      float4 alA = sh_al[hw][j];     int sA = sh_src[hw][j];     float cfA = sh_cf[hw][j];
      float4 alB = sh_al[hw][j + 1]; int sB = sh_src[hw][j + 1]; float cfB = sh_cf[hw][j + 1];
      ushort4 xA = *(const ushort4*)(xb + ((size_t)sA << 7) + (lh << 2));
      ushort4 xB = *(const ushort4*)(xb + ((size_t)sB << 7) + (lh << 2));
      float fa[4] = {bf2f(xA.x), bf2f(xA.y), bf2f(xA.z), bf2f(xA.w)};
      float fb[4] = {bf2f(xB.x), bf2f(xB.y), bf2f(xB.z), bf2f(xB.w)};
      float aA[4] = {alA.x, alA.y, alA.z, alA.w};
      float aB[4] = {alB.x, alB.y, alB.z, alB.w};
      #pragma unroll
      for (int h = 0; h < 4; ++h)
        #pragma unroll
        for (int d = 0; d < 4; ++d)
          ug[h][d] += aA[h] * fa[d] + aB[h] * fb[d];
      #pragma unroll
      for (int d = 0; d < 4; ++d)
        vg[d] += cfA * fa[d] + cfB * fb[d];
    }
  }

  #pragma unroll
  for (int off = 16; off; off >>= 1) {
    den0 += __shfl_xor(den0, off); den1 += __shfl_xor(den1, off);
    den2 += __shfl_xor(den2, off); den3 += __shfl_xor(den3, off);
  }
  const float r[4] = {1.f / den0, 1.f / den1, 1.f / den2, 1.f / den3};
  const float dn = dinv[n];
  unsigned short* uvp = UV + (size_t)n * 640;
  #pragma unroll
  for (int h = 0; h < 4; ++h) {
    ushort4 u;
    u.x = f2bf(ug[h][0] * r[h]); u.y = f2bf(ug[h][1] * r[h]);
    u.z = f2bf(ug[h][2] * r[h]); u.w = f2bf(ug[h][3] * r[h]);
    *(ushort4*)(uvp + h * 128 + 4 * lh) = u;
  }
  ushort4 v4;
  v4.x = f2bf(vg[0] * dn); v4.y = f2bf(vg[1] * dn);
  v4.z = f2bf(vg[2] * dn); v4.w = f2bf(vg[3] * dn);
  *(ushort4*)(uvp + 512 + 4 * lh) = v4;
}

// ---------------- MFMA GEMM 2 (v2): round-2 structure, K-chunked ----------------
// grid (235, 4): y in {0,1} gat col-halves (K=512, 4 chunks); y in {2,3} gcn
// col-halves (K=128, 1 chunk, A at UV short-offset 512). BM=128, BN=64, 48KB LDS.
__global__ __launch_bounds__(256) void k_gemm2(
    const unsigned short* __restrict__ UV,
    const unsigned short* __restrict__ Wt2g, const unsigned short* __restrict__ Wt2c,
    unsigned short* __restrict__ acc_g, unsigned short* __restrict__ acc_c, int N)
{
  __shared__ unsigned short As[128 * 128];  // [row][k], 16B-block kb ^= row&7
  __shared__ unsigned short Bs[64 * 128];   // [col][k], 16B-block kb ^= col&7
  const int t = threadIdx.x;
  const int m0 = blockIdx.x * 128;
  const int y = blockIdx.y;
  const bool is_gat = (y < 2);
  const int c0 = (y & 1) * 64;
  const unsigned short* Bsrc = is_gat ? (Wt2g + (size_t)c0 * 512)
                                      : (Wt2c + (size_t)c0 * 128);
  const int bstride = is_gat ? 512 : 128;
  const int nchunks = is_gat ? 4 : 1;
  const int abase = is_gat ? 0 : 512;   // short offset within UV row

  const int w = t >> 6, l = t & 63;
  const int wr = w >> 1, wc = w & 1;
  const int lrow = l & 15, lk = l >> 4;

  f32x4 acc[4][2];
  #pragma unroll
  for (int m = 0; m < 4; ++m)
    #pragma unroll
    for (int n = 0; n < 2; ++n) acc[m][n] = (f32x4){0.f, 0.f, 0.f, 0.f};

  for (int kt = 0; kt < nchunks; ++kt) {
    __syncthreads();
    // stage A chunk: 128 rows x 128 k bf16 = 2048 uint4
    #pragma unroll
    for (int i = 0; i < 8; ++i) {
      int g = i * 256 + t;
      int row = g >> 4, kb = g & 15;
      int gr = m0 + row;
      uint4 v = make_uint4(0u, 0u, 0u, 0u);
      if (gr < N) v = *(const uint4*)(UV + (size_t)gr * 640 + abase + kt * 128 + kb * 8);
      *(uint4*)&As[row * 128 + ((kb ^ (row & 7)) << 3)] = v;
    }
    // stage B chunk: 64 cols x 128 k bf16 = 1024 uint4
    #pragma unroll
    for (int i = 0; i < 4; ++i) {
      int g = i * 256 + t;
      int col = g >> 4, kb = g & 15;
      uint4 v = *(const uint4*)(Bsrc + (size_t)col * bstride + kt * 128 + kb * 8);
      *(uint4*)&Bs[col * 128 + ((kb ^ (col & 7)) << 3)] = v;
    }
    __syncthreads();
    #pragma unroll
    for (int ks = 0; ks < 4; ++ks) {
      int kb = ks * 4 + lk;
      bf16x8 a[4], b[2];
      #pragma unroll
      for (int m = 0; m < 4; ++m) {
        int row = wr * 64 + m * 16 + lrow;
        a[m] = *(const bf16x8*)&As[row * 128 + ((kb ^ (row & 7)) << 3)];
      }
      #pragma unroll
      for (int n = 0; n < 2; ++n) {
        int col = wc * 32 + n * 16 + lrow;
        b[n] = *(const bf16x8*)&Bs[col * 128 + ((kb ^ (col & 7)) << 3)];
      }
      #pragma unroll
      for (int m = 0; m < 4; ++m)
        #pragma unroll
        for (int n = 0; n < 2; ++n)
          acc[m][n] = __builtin_amdgcn_mfma_f32_16x16x32_bf16(a[m], b[n], acc[m][n], 0, 0, 0);
    }
  }

  unsigned short* dst = is_gat ? acc_g : acc_c;
  #pragma unroll
  for (int m = 0; m < 4; ++m) {
    #pragma unroll
    for (int n = 0; n < 2; ++n) {
      int col = c0 + wc * 32 + n * 16 + lrow;
      #pragma unroll
      for (int j = 0; j < 4; ++j) {
        int r = m0 + wr * 64 + m * 16 + lk * 4 + j;
        if (r >= N) continue;
        dst[(size_t)r * 128 + col] = f2bf(acc[m][n][j]);
      }
    }
  }
}

// ---------------- gate + residual + LayerNorm ----------------------------------
__global__ __launch_bounds__(256) void k_final(
    const unsigned short* __restrict__ acc_g, const unsigned short* __restrict__ acc_c,
    const float* __restrict__ b_gat, const float* __restrict__ b_gcn,
    const float* __restrict__ W_gate, const float* __restrict__ b_gate,
    const float* __restrict__ gamma, const float* __restrict__ beta,
    float* __restrict__ out, int N)
{
  int n = blockIdx.x * 4 + (threadIdx.x >> 6);
  if (n >= N) return;
  int l = threadIdx.x & 63;
  ushort2 gau = *(const ushort2*)(acc_g + (size_t)n * 128 + 2 * l);
  ushort2 gcu = *(const ushort2*)(acc_c + (size_t)n * 128 + 2 * l);
  float2 ga = make_float2(bf2f(gau.x), bf2f(gau.y));
  float2 gc = make_float2(bf2f(gcu.x), bf2f(gcu.y));
  float2 bg = ((const float2*)b_gat)[l];
  float2 bc = ((const float2*)b_gcn)[l];
  float g0x = ga.x * 0.25f + bg.x, g0y = ga.y * 0.25f + bg.y;
  float c0x = gc.x + bc.x,         c0y = gc.y + bc.y;
  float4 wa = ((const float4*)W_gate)[l];        // rows 2l, 2l+1
  float4 wc = ((const float4*)W_gate)[64 + l];   // rows 128+2l, 128+2l+1
  float z0 = g0x * wa.x + g0y * wa.z + c0x * wc.x + c0y * wc.z;
  float z1 = g0x * wa.y + g0y * wa.w + c0x * wc.y + c0y * wc.w;
  #pragma unroll
  for (int off = 32; off; off >>= 1) { z0 += __shfl_xor(z0, off); z1 += __shfl_xor(z1, off); }
  z0 += b_gate[0]; z1 += b_gate[1];
  float mz = fmaxf(z0, z1);
  float ez0 = __expf(z0 - mz), ez1 = __expf(z1 - mz);
  float inv = 1.f / (ez0 + ez1);
  float w0 = ez0 * inv, w1 = ez1 * inv;
  float hx = (1.f + w0) * g0x + w1 * c0x;   // fused + gat_out
  float hy = (1.f + w0) * g0y + w1 * c0y;
  float ssum = hx + hy;
  #pragma unroll
  for (int off = 32; off; off >>= 1) ssum += __shfl_xor(ssum, off);
  float mu = ssum * (1.f / 128.f);
  float vx = hx - mu, vy = hy - mu;
  float vsum = vx * vx + vy * vy;
  #pragma unroll
  for (int off = 32; off; off >>= 1) vsum += __shfl_xor(vsum, off);
  float rstd = rsqrtf(vsum * (1.f / 128.f) + LN_EPS);
  float2 gm = ((const float2*)gamma)[l];
  float2 bt = ((const float2*)beta)[l];
  float2 o;
  o.x = vx * rstd * gm.x + bt.x;
  o.y = vy * rstd * gm.y + bt.y;
  ((float2*)out)[(size_t)n * 64 + l] = o;
}

extern "C" void kernel_launch(void* const* d_in, const int* in_sizes, int n_in,
                              void* d_out, int out_size, void* d_ws, size_t ws_size,
                              hipStream_t stream)
{
  const float* x       = (const float*)d_in[0];
  const int*   ei      = (const int*)d_in[1];
  const float* Wgat    = (const float*)d_in[2];
  const float* att_src = (const float*)d_in[3];
  const float* att_dst = (const float*)d_in[4];
  const float* b_gat   = (const float*)d_in[5];
  const float* Wgcn    = (const float*)d_in[6];
  const float* b_gcn   = (const float*)d_in[7];
  const float* W_gate  = (const float*)d_in[8];
  const float* b_gate  = (const float*)d_in[9];
  const float* gamma   = (const float*)d_in[10];
  const float* beta    = (const float*)d_in[11];
  float* out = (float*)d_out;

  const int N  = in_sizes[0] / D;   // 30000
  const int E  = in_sizes[1] / 2;   // 480000
  const int Et = E + N;

  char* p = (char*)d_ws;
  unsigned short* xb   = (unsigned short*)p; p += (size_t)N * D * 2;        // 7.7MB
  unsigned short* UV   = (unsigned short*)p; p += (size_t)N * 640 * 2;      // 38.4MB
  unsigned short* Wt2g = (unsigned short*)p; p += (size_t)128 * 512 * 2;
  unsigned short* Wt2c = (unsigned short*)p; p += (size_t)128 * 128 * 2;
  unsigned short* accg = (unsigned short*)p; p += (size_t)N * D * 2;        // 7.7MB
  unsigned short* accc = (unsigned short*)p; p += (size_t)N * D * 2;        // 7.7MB
  float* wtil_s  = (float*)p; p += 512 * 4;
  float* wtil_d  = (float*)p; p += 512 * 4;
  float* a_s     = (float*)p; p += (size_t)N * NH * 4;
  float* a_d     = (float*)p; p += (size_t)N * NH * 4;
  float* dinv    = (float*)p; p += (size_t)N * 4;
  int* deg       = (int*)p;   p += (size_t)N * 4;
  int* row_ptr   = (int*)p;   p += (size_t)(N + 1) * 4;
  int* cursor    = (int*)p;   p += (size_t)N * 4;
  int* col_src   = (int*)p;   p += (size_t)Et * 4;
  int* bsum      = (int*)p;   p += 1024;

  hipMemsetAsync(deg, 0, (size_t)N * 4, stream);

  k_prep_w2<<<256, 128, 0, stream>>>(Wgat, Wgcn, Wt2g, Wt2c);
  k_wtilde<<<8, 128, 0, stream>>>(Wgat, att_src, att_dst, wtil_s, wtil_d);
  k_xb<<<(N + 3) / 4, 256, 0, stream>>>(x, wtil_s, wtil_d, xb, a_s, a_d, N);
  k_deg<<<(Et + 255) / 256, 256, 0, stream>>>(ei, E, N, deg);
  int nb = (N + 255) / 256;
  k_scan1<<<nb, 256, 0, stream>>>(deg, N, bsum);
  k_scan2<<<1, 128, 0, stream>>>(bsum, nb);
  k_scan3<<<nb, 256, 0, stream>>>(deg, bsum, N, Et, row_ptr, cursor, dinv);
  k_fill<<<(Et + 255) / 256, 256, 0, stream>>>(ei, E, N, cursor, col_src);
  k_agg2<<<(N + 7) / 8, 256, 0, stream>>>(xb, a_s, a_d, row_ptr, col_src, dinv, UV, N);
  dim3 gg2((N + 127) / 128, 4);
  k_gemm2<<<gg2, 256, 0, stream>>>(UV, Wt2g, Wt2c, accg, accc, N);
  k_final<<<(N + 3) / 4, 256, 0, stream>>>(accg, accc, b_gat, b_gcn,
                                            W_gate, b_gate, gamma, beta, out, N);
  (void)n_in; (void)out_size; (void)ws_size;
}

// Round 8
// 148.936 us; speedup vs baseline: 1.5308x; 1.0177x over previous
//
#include <hip/hip_runtime.h>
#include <hip/hip_bf16.h>

#define D 128
#define NH 4
#define NEG_SLOPE 0.2f
#define LN_EPS 1e-5f

typedef __attribute__((ext_vector_type(4))) float f32x4;
typedef __attribute__((ext_vector_type(8))) short bf16x8;

__device__ __forceinline__ float bf2f(unsigned short u) {
  union { unsigned int i; float f; } c; c.i = ((unsigned int)u) << 16; return c.f;
}
__device__ __forceinline__ unsigned short f2bf(float f) {
  union { float f; unsigned int i; } c; c.f = f;
  unsigned int r = c.i + 0x7FFFu + ((c.i >> 16) & 1u);  // RNE
  return (unsigned short)(r >> 16);
}

// ---------------- weight prep ---------------------------------------------------
// Wt2g[c][k] = W_gat[h=k>>7][k&127][c]  (c in [0,128), k in [0,512))  bf16
// Wt2c[c][k] = W_gcn[k][c]              (k in [0,128))                bf16
__global__ __launch_bounds__(128) void k_prep_w2(
    const float* __restrict__ Wgat, const float* __restrict__ Wgcn,
    unsigned short* __restrict__ Wt2g, unsigned short* __restrict__ Wt2c)
{
  int c = blockIdx.x, t = threadIdx.x;
  if (c < 128) {
    #pragma unroll
    for (int i = 0; i < 4; ++i) {
      int k = t + i * 128;
      int h = k >> 7, kk = k & 127;
      Wt2g[c * 512 + k] = f2bf(Wgat[((size_t)h * D + kk) * D + c]);
    }
  } else {
    int cc = c - 128;
    Wt2c[cc * 128 + t] = f2bf(Wgcn[(size_t)t * D + cc]);
  }
}

// wtil_s[h*128+k] = sum_f W_gat[h][k][f] * att_src[h][f]; wtil_d same with att_dst
__global__ __launch_bounds__(128) void k_wtilde(
    const float* __restrict__ Wgat,
    const float* __restrict__ att_src, const float* __restrict__ att_dst,
    float* __restrict__ wtil_s, float* __restrict__ wtil_d)
{
  int h = blockIdx.x >> 1, which = blockIdx.x & 1;
  int k = threadIdx.x;
  const float* av = (which ? att_dst : att_src) + h * D;
  const float* Wrow = Wgat + ((size_t)h * D + k) * D;
  float s = 0.f;
  for (int f = 0; f < D; ++f) s += Wrow[f] * av[f];
  (which ? wtil_d : wtil_s)[h * D + k] = s;
}

// ---------------- x -> bf16 copy + attention dots + deg zeroing -----------------
__global__ __launch_bounds__(256) void k_xb(
    const float* __restrict__ x,
    const float* __restrict__ wtil_s, const float* __restrict__ wtil_d,
    unsigned short* __restrict__ xb, float* __restrict__ a_s, float* __restrict__ a_d,
    int* __restrict__ deg, int N)
{
  const int w = threadIdx.x >> 6, l = threadIdx.x & 63;
  const int n = blockIdx.x * 4 + w;
  if (n >= N) return;
  if (l == 0) deg[n] = 0;   // replaces hipMemsetAsync (runs before k_deg on stream)
  float2 xv = ((const float2*)(x + (size_t)n * D))[l];
  ushort2 p; p.x = f2bf(xv.x); p.y = f2bf(xv.y);
  *(ushort2*)(xb + (size_t)n * D + 2 * l) = p;
  float s0 = xv.x * wtil_s[2*l]       + xv.y * wtil_s[2*l+1];
  float s1 = xv.x * wtil_s[D+2*l]     + xv.y * wtil_s[D+2*l+1];
  float s2 = xv.x * wtil_s[2*D+2*l]   + xv.y * wtil_s[2*D+2*l+1];
  float s3 = xv.x * wtil_s[3*D+2*l]   + xv.y * wtil_s[3*D+2*l+1];
  float d0 = xv.x * wtil_d[2*l]       + xv.y * wtil_d[2*l+1];
  float d1 = xv.x * wtil_d[D+2*l]     + xv.y * wtil_d[D+2*l+1];
  float d2 = xv.x * wtil_d[2*D+2*l]   + xv.y * wtil_d[2*D+2*l+1];
  float d3 = xv.x * wtil_d[3*D+2*l]   + xv.y * wtil_d[3*D+2*l+1];
  #pragma unroll
  for (int off = 32; off; off >>= 1) {
    s0 += __shfl_xor(s0, off); s1 += __shfl_xor(s1, off);
    s2 += __shfl_xor(s2, off); s3 += __shfl_xor(s3, off);
    d0 += __shfl_xor(d0, off); d1 += __shfl_xor(d1, off);
    d2 += __shfl_xor(d2, off); d3 += __shfl_xor(d3, off);
  }
  if (l == 0) {
    ((float4*)a_s)[n] = make_float4(s0, s1, s2, s3);
    ((float4*)a_d)[n] = make_float4(d0, d1, d2, d3);
  }
}

// ---------------- CSR build ----------------------------------------------------
__global__ void k_deg(const int* __restrict__ ei, int E, int N, int* __restrict__ deg)
{
  int e = blockIdx.x * blockDim.x + threadIdx.x;
  if (e >= E + N) return;
  int dst = (e < E) ? ei[E + e] : (e - E);
  atomicAdd(&deg[dst], 1);
}

__global__ void k_scan1(const int* __restrict__ deg, int N, int* __restrict__ bsum)
{
  __shared__ int s[256];
  int t = threadIdx.x;
  int i = blockIdx.x * 256 + t;
  s[t] = (i < N) ? deg[i] : 0;
  __syncthreads();
  for (int off = 128; off; off >>= 1) {
    if (t < off) s[t] += s[t + off];
    __syncthreads();
  }
  if (t == 0) bsum[blockIdx.x] = s[0];
}

__global__ void k_scan2(int* __restrict__ bsum, int nb)
{
  __shared__ int s[128];
  int t = threadIdx.x;
  int v = (t < nb) ? bsum[t] : 0;
  s[t] = v; __syncthreads();
  for (int off = 1; off < 128; off <<= 1) {
    int xv = (t >= off) ? s[t - off] : 0;
    __syncthreads();
    s[t] += xv;
    __syncthreads();
  }
  if (t < nb) bsum[t] = s[t] - v;   // exclusive
}

__global__ void k_scan3(const int* __restrict__ deg, const int* __restrict__ bsum,
                        int N, int Et, int* __restrict__ row_ptr,
                        int* __restrict__ cursor, float* __restrict__ dinv)
{
  __shared__ int s[256];
  int t = threadIdx.x;
  int i = blockIdx.x * 256 + t;
  int v = (i < N) ? deg[i] : 0;
  s[t] = v; __syncthreads();
  for (int off = 1; off < 256; off <<= 1) {
    int xv = (t >= off) ? s[t - off] : 0;
    __syncthreads();
    s[t] += xv;
    __syncthreads();
  }
  if (i < N) {
    int excl = s[t] - v + bsum[blockIdx.x];
    row_ptr[i] = excl;
    cursor[i] = excl;
    dinv[i] = rsqrtf((float)v);    // deg >= 1 (self-loop)
  }
  if (i == 0) row_ptr[N] = Et;
}

__global__ void k_fill(const int* __restrict__ ei, int E, int N,
                       int* __restrict__ cursor, int* __restrict__ col_src)
{
  int e = blockIdx.x * blockDim.x + threadIdx.x;
  if (e >= E + N) return;
  int src, dst;
  if (e < E) { src = ei[e]; dst = ei[E + e]; }
  else       { src = e - E; dst = src; }
  int pos = atomicAdd(&cursor[dst], 1);
  col_src[pos] = src;
}

// ---------------- x-domain aggregation ------------------------------------------
// Half-wave per node (lane owns 4 dims of 128). Per edge gather ONLY xb (256B).
// Accumulate 4 head-weighted sums + 1 coef-weighted sum; normalize at end; write
// UV[n][640] bf16 (U: k=h*128+d, V: k=512+d).
__global__ __launch_bounds__(256) void k_agg2(
    const unsigned short* __restrict__ xb,
    const float* __restrict__ a_s, const float* __restrict__ a_d,
    const int* __restrict__ row_ptr, const int* __restrict__ col_src,
    const float* __restrict__ dinv,
    unsigned short* __restrict__ UV, int N)
{
  __shared__ float4 sh_al[8][33];
  __shared__ int    sh_src[8][33];
  __shared__ float  sh_cf[8][33];
  const int hw = threadIdx.x >> 5, lh = threadIdx.x & 31;
  const int n = blockIdx.x * 8 + hw;
  if (n >= N) return;
  const int start = row_ptr[n], end = row_ptr[n + 1];
  const float4 adn = ((const float4*)a_d)[n];

  float den0 = 0.f, den1 = 0.f, den2 = 0.f, den3 = 0.f;
  float ug[4][4] = {};
  float vg[4] = {};

  for (int base = start; base < end; base += 32) {
    const int cnt = min(32, end - base);
    if (lh < cnt) {
      int s = col_src[base + lh];
      float4 as4 = ((const float4*)a_s)[s];
      float e0 = as4.x + adn.x; e0 = (e0 >= 0.f) ? e0 : NEG_SLOPE * e0;
      float e1 = as4.y + adn.y; e1 = (e1 >= 0.f) ? e1 : NEG_SLOPE * e1;
      float e2 = as4.z + adn.z; e2 = (e2 >= 0.f) ? e2 : NEG_SLOPE * e2;
      float e3 = as4.w + adn.w; e3 = (e3 >= 0.f) ? e3 : NEG_SLOPE * e3;
      float x0 = __expf(e0), x1 = __expf(e1), x2 = __expf(e2), x3 = __expf(e3);
      den0 += x0; den1 += x1; den2 += x2; den3 += x3;
      sh_al[hw][lh] = make_float4(x0, x1, x2, x3);
      sh_src[hw][lh] = s;
      sh_cf[hw][lh] = dinv[s];
    }
    if (lh == 0) {   // sentinel
      sh_al[hw][cnt] = make_float4(0.f, 0.f, 0.f, 0.f);
      sh_src[hw][cnt] = 0;
      sh_cf[hw][cnt] = 0.f;
    }
    for (int j = 0; j < cnt; j += 2) {
      float4 alA = sh_al[hw][j];     int sA = sh_src[hw][j];     float cfA = sh_cf[hw][j];
      float4 alB = sh_al[hw][j + 1]; int sB = sh_src[hw][j + 1]; float cfB = sh_cf[hw][j + 1];
      ushort4 xA = *(const ushort4*)(xb + ((size_t)sA << 7) + (lh << 2));
      ushort4 xB = *(const ushort4*)(xb + ((size_t)sB << 7) + (lh << 2));
      float fa[4] = {bf2f(xA.x), bf2f(xA.y), bf2f(xA.z), bf2f(xA.w)};
      float fb[4] = {bf2f(xB.x), bf2f(xB.y), bf2f(xB.z), bf2f(xB.w)};
      float aA[4] = {alA.x, alA.y, alA.z, alA.w};
      float aB[4] = {alB.x, alB.y, alB.z, alB.w};
      #pragma unroll
      for (int h = 0; h < 4; ++h)
        #pragma unroll
        for (int d = 0; d < 4; ++d)
          ug[h][d] += aA[h] * fa[d] + aB[h] * fb[d];
      #pragma unroll
      for (int d = 0; d < 4; ++d)
        vg[d] += cfA * fa[d] + cfB * fb[d];
    }
  }

  #pragma unroll
  for (int off = 16; off; off >>= 1) {
    den0 += __shfl_xor(den0, off); den1 += __shfl_xor(den1, off);
    den2 += __shfl_xor(den2, off); den3 += __shfl_xor(den3, off);
  }
  const float r[4] = {1.f / den0, 1.f / den1, 1.f / den2, 1.f / den3};
  const float dn = dinv[n];
  unsigned short* uvp = UV + (size_t)n * 640;
  #pragma unroll
  for (int h = 0; h < 4; ++h) {
    ushort4 u;
    u.x = f2bf(ug[h][0] * r[h]); u.y = f2bf(ug[h][1] * r[h]);
    u.z = f2bf(ug[h][2] * r[h]); u.w = f2bf(ug[h][3] * r[h]);
    *(ushort4*)(uvp + h * 128 + 4 * lh) = u;
  }
  ushort4 v4;
  v4.x = f2bf(vg[0] * dn); v4.y = f2bf(vg[1] * dn);
  v4.z = f2bf(vg[2] * dn); v4.w = f2bf(vg[3] * dn);
  *(ushort4*)(uvp + 512 + 4 * lh) = v4;
}

// ---------------- MFMA GEMM 2 (v2): round-2 structure, K-chunked ----------------
// grid (235, 4): y in {0,1} gat col-halves (K=512, 4 chunks); y in {2,3} gcn
// col-halves (K=128, 1 chunk, A at UV short-offset 512). BM=128, BN=64, 48KB LDS.
__global__ __launch_bounds__(256) void k_gemm2(
    const unsigned short* __restrict__ UV,
    const unsigned short* __restrict__ Wt2g, const unsigned short* __restrict__ Wt2c,
    unsigned short* __restrict__ acc_g, unsigned short* __restrict__ acc_c, int N)
{
  __shared__ unsigned short As[128 * 128];  // [row][k], 16B-block kb ^= row&7
  __shared__ unsigned short Bs[64 * 128];   // [col][k], 16B-block kb ^= col&7
  const int t = threadIdx.x;
  const int m0 = blockIdx.x * 128;
  const int y = blockIdx.y;
  const bool is_gat = (y < 2);
  const int c0 = (y & 1) * 64;
  const unsigned short* Bsrc = is_gat ? (Wt2g + (size_t)c0 * 512)
                                      : (Wt2c + (size_t)c0 * 128);
  const int bstride = is_gat ? 512 : 128;
  const int nchunks = is_gat ? 4 : 1;
  const int abase = is_gat ? 0 : 512;   // short offset within UV row

  const int w = t >> 6, l = t & 63;
  const int wr = w >> 1, wc = w & 1;
  const int lrow = l & 15, lk = l >> 4;

  f32x4 acc[4][2];
  #pragma unroll
  for (int m = 0; m < 4; ++m)
    #pragma unroll
    for (int n = 0; n < 2; ++n) acc[m][n] = (f32x4){0.f, 0.f, 0.f, 0.f};

  for (int kt = 0; kt < nchunks; ++kt) {
    __syncthreads();
    // stage A chunk: 128 rows x 128 k bf16 = 2048 uint4
    #pragma unroll
    for (int i = 0; i < 8; ++i) {
      int g = i * 256 + t;
      int row = g >> 4, kb = g & 15;
      int gr = m0 + row;
      uint4 v = make_uint4(0u, 0u, 0u, 0u);
      if (gr < N) v = *(const uint4*)(UV + (size_t)gr * 640 + abase + kt * 128 + kb * 8);
      *(uint4*)&As[row * 128 + ((kb ^ (row & 7)) << 3)] = v;
    }
    // stage B chunk: 64 cols x 128 k bf16 = 1024 uint4
    #pragma unroll
    for (int i = 0; i < 4; ++i) {
      int g = i * 256 + t;
      int col = g >> 4, kb = g & 15;
      uint4 v = *(const uint4*)(Bsrc + (size_t)col * bstride + kt * 128 + kb * 8);
      *(uint4*)&Bs[col * 128 + ((kb ^ (col & 7)) << 3)] = v;
    }
    __syncthreads();
    #pragma unroll
    for (int ks = 0; ks < 4; ++ks) {
      int kb = ks * 4 + lk;
      bf16x8 a[4], b[2];
      #pragma unroll
      for (int m = 0; m < 4; ++m) {
        int row = wr * 64 + m * 16 + lrow;
        a[m] = *(const bf16x8*)&As[row * 128 + ((kb ^ (row & 7)) << 3)];
      }
      #pragma unroll
      for (int n = 0; n < 2; ++n) {
        int col = wc * 32 + n * 16 + lrow;
        b[n] = *(const bf16x8*)&Bs[col * 128 + ((kb ^ (col & 7)) << 3)];
      }
      #pragma unroll
      for (int m = 0; m < 4; ++m)
        #pragma unroll
        for (int n = 0; n < 2; ++n)
          acc[m][n] = __builtin_amdgcn_mfma_f32_16x16x32_bf16(a[m], b[n], acc[m][n], 0, 0, 0);
    }
  }

  unsigned short* dst = is_gat ? acc_g : acc_c;
  #pragma unroll
  for (int m = 0; m < 4; ++m) {
    #pragma unroll
    for (int n = 0; n < 2; ++n) {
      int col = c0 + wc * 32 + n * 16 + lrow;
      #pragma unroll
      for (int j = 0; j < 4; ++j) {
        int r = m0 + wr * 64 + m * 16 + lk * 4 + j;
        if (r >= N) continue;
        dst[(size_t)r * 128 + col] = f2bf(acc[m][n][j]);
      }
    }
  }
}

// ---------------- gate + residual + LayerNorm ----------------------------------
__global__ __launch_bounds__(256) void k_final(
    const unsigned short* __restrict__ acc_g, const unsigned short* __restrict__ acc_c,
    const float* __restrict__ b_gat, const float* __restrict__ b_gcn,
    const float* __restrict__ W_gate, const float* __restrict__ b_gate,
    const float* __restrict__ gamma, const float* __restrict__ beta,
    float* __restrict__ out, int N)
{
  int n = blockIdx.x * 4 + (threadIdx.x >> 6);
  if (n >= N) return;
  int l = threadIdx.x & 63;
  ushort2 gau = *(const ushort2*)(acc_g + (size_t)n * 128 + 2 * l);
  ushort2 gcu = *(const ushort2*)(acc_c + (size_t)n * 128 + 2 * l);
  float2 ga = make_float2(bf2f(gau.x), bf2f(gau.y));
  float2 gc = make_float2(bf2f(gcu.x), bf2f(gcu.y));
  float2 bg = ((const float2*)b_gat)[l];
  float2 bc = ((const float2*)b_gcn)[l];
  float g0x = ga.x * 0.25f + bg.x, g0y = ga.y * 0.25f + bg.y;
  float c0x = gc.x + bc.x,         c0y = gc.y + bc.y;
  float4 wa = ((const float4*)W_gate)[l];        // rows 2l, 2l+1
  float4 wc = ((const float4*)W_gate)[64 + l];   // rows 128+2l, 128+2l+1
  float z0 = g0x * wa.x + g0y * wa.z + c0x * wc.x + c0y * wc.z;
  float z1 = g0x * wa.y + g0y * wa.w + c0x * wc.y + c0y * wc.w;
  #pragma unroll
  for (int off = 32; off; off >>= 1) { z0 += __shfl_xor(z0, off); z1 += __shfl_xor(z1, off); }
  z0 += b_gate[0]; z1 += b_gate[1];
  float mz = fmaxf(z0, z1);
  float ez0 = __expf(z0 - mz), ez1 = __expf(z1 - mz);
  float inv = 1.f / (ez0 + ez1);
  float w0 = ez0 * inv, w1 = ez1 * inv;
  float hx = (1.f + w0) * g0x + w1 * c0x;   // fused + gat_out
  float hy = (1.f + w0) * g0y + w1 * c0y;
  float ssum = hx + hy;
  #pragma unroll
  for (int off = 32; off; off >>= 1) ssum += __shfl_xor(ssum, off);
  float mu = ssum * (1.f / 128.f);
  float vx = hx - mu, vy = hy - mu;
  float vsum = vx * vx + vy * vy;
  #pragma unroll
  for (int off = 32; off; off >>= 1) vsum += __shfl_xor(vsum, off);
  float rstd = rsqrtf(vsum * (1.f / 128.f) + LN_EPS);
  float2 gm = ((const float2*)gamma)[l];
  float2 bt = ((const float2*)beta)[l];
  float2 o;
  o.x = vx * rstd * gm.x + bt.x;
  o.y = vy * rstd * gm.y + bt.y;
  ((float2*)out)[(size_t)n * 64 + l] = o;
}

extern "C" void kernel_launch(void* const* d_in, const int* in_sizes, int n_in,
                              void* d_out, int out_size, void* d_ws, size_t ws_size,
                              hipStream_t stream)
{
  const float* x       = (const float*)d_in[0];
  const int*   ei      = (const int*)d_in[1];
  const float* Wgat    = (const float*)d_in[2];
  const float* att_src = (const float*)d_in[3];
  const float* att_dst = (const float*)d_in[4];
  const float* b_gat   = (const float*)d_in[5];
  const float* Wgcn    = (const float*)d_in[6];
  const float* b_gcn   = (const float*)d_in[7];
  const float* W_gate  = (const float*)d_in[8];
  const float* b_gate  = (const float*)d_in[9];
  const float* gamma   = (const float*)d_in[10];
  const float* beta    = (const float*)d_in[11];
  float* out = (float*)d_out;

  const int N  = in_sizes[0] / D;   // 30000
  const int E  = in_sizes[1] / 2;   // 480000
  const int Et = E + N;

  char* p = (char*)d_ws;
  unsigned short* xb   = (unsigned short*)p; p += (size_t)N * D * 2;        // 7.7MB
  unsigned short* UV   = (unsigned short*)p; p += (size_t)N * 640 * 2;      // 38.4MB
  unsigned short* Wt2g = (unsigned short*)p; p += (size_t)128 * 512 * 2;
  unsigned short* Wt2c = (unsigned short*)p; p += (size_t)128 * 128 * 2;
  unsigned short* accg = (unsigned short*)p; p += (size_t)N * D * 2;        // 7.7MB
  unsigned short* accc = (unsigned short*)p; p += (size_t)N * D * 2;        // 7.7MB
  float* wtil_s  = (float*)p; p += 512 * 4;
  float* wtil_d  = (float*)p; p += 512 * 4;
  float* a_s     = (float*)p; p += (size_t)N * NH * 4;
  float* a_d     = (float*)p; p += (size_t)N * NH * 4;
  float* dinv    = (float*)p; p += (size_t)N * 4;
  int* deg       = (int*)p;   p += (size_t)N * 4;
  int* row_ptr   = (int*)p;   p += (size_t)(N + 1) * 4;
  int* cursor    = (int*)p;   p += (size_t)N * 4;
  int* col_src   = (int*)p;   p += (size_t)Et * 4;
  int* bsum      = (int*)p;   p += 1024;

  k_prep_w2<<<256, 128, 0, stream>>>(Wgat, Wgcn, Wt2g, Wt2c);
  k_wtilde<<<8, 128, 0, stream>>>(Wgat, att_src, att_dst, wtil_s, wtil_d);
  k_xb<<<(N + 3) / 4, 256, 0, stream>>>(x, wtil_s, wtil_d, xb, a_s, a_d, deg, N);
  k_deg<<<(Et + 255) / 256, 256, 0, stream>>>(ei, E, N, deg);
  int nb = (N + 255) / 256;
  k_scan1<<<nb, 256, 0, stream>>>(deg, N, bsum);
  k_scan2<<<1, 128, 0, stream>>>(bsum, nb);
  k_scan3<<<nb, 256, 0, stream>>>(deg, bsum, N, Et, row_ptr, cursor, dinv);
  k_fill<<<(Et + 255) / 256, 256, 0, stream>>>(ei, E, N, cursor, col_src);
  k_agg2<<<(N + 7) / 8, 256, 0, stream>>>(xb, a_s, a_d, row_ptr, col_src, dinv, UV, N);
  dim3 gg2((N + 127) / 128, 4);
  k_gemm2<<<gg2, 256, 0, stream>>>(UV, Wt2g, Wt2c, accg, accc, N);
  k_final<<<(N + 3) / 4, 256, 0, stream>>>(accg, accc, b_gat, b_gcn,
                                            W_gate, b_gate, gamma, beta, out, N);
  (void)n_in; (void)out_size; (void)ws_size;
}

// Round 9
// 145.414 us; speedup vs baseline: 1.5679x; 1.0242x over previous
//
#include <hip/hip_runtime.h>
#include <hip/hip_bf16.h>

#define D 128
#define NH 4
#define NEG_SLOPE 0.2f
#define LN_EPS 1e-5f

typedef __attribute__((ext_vector_type(4))) float f32x4;
typedef __attribute__((ext_vector_type(8))) short bf16x8;

__device__ __forceinline__ float bf2f(unsigned short u) {
  union { unsigned int i; float f; } c; c.i = ((unsigned int)u) << 16; return c.f;
}
__device__ __forceinline__ unsigned short f2bf(float f) {
  union { float f; unsigned int i; } c; c.f = f;
  unsigned int r = c.i + 0x7FFFu + ((c.i >> 16) & 1u);  // RNE
  return (unsigned short)(r >> 16);
}

// ---------------- weight prep (merged): Wt2g, Wt2c, wtil_s, wtil_d --------------
// blocks 0..127: Wt2g[c][k] = W_gat[k>>7][k&127][c]; 128..255: Wt2c[c][k]=Wgcn[k][c]
// blocks 256..263: wtil_{s,d}[h*128+k] = sum_f W_gat[h][k][f]*att_{src,dst}[h][f]
__global__ __launch_bounds__(128) void k_prep(
    const float* __restrict__ Wgat, const float* __restrict__ Wgcn,
    const float* __restrict__ att_src, const float* __restrict__ att_dst,
    unsigned short* __restrict__ Wt2g, unsigned short* __restrict__ Wt2c,
    float* __restrict__ wtil_s, float* __restrict__ wtil_d)
{
  int c = blockIdx.x, t = threadIdx.x;
  if (c < 128) {
    #pragma unroll
    for (int i = 0; i < 4; ++i) {
      int k = t + i * 128;
      int h = k >> 7, kk = k & 127;
      Wt2g[c * 512 + k] = f2bf(Wgat[((size_t)h * D + kk) * D + c]);
    }
  } else if (c < 256) {
    int cc = c - 128;
    Wt2c[cc * 128 + t] = f2bf(Wgcn[(size_t)t * D + cc]);
  } else {
    int b2 = c - 256;
    int h = b2 >> 1, which = b2 & 1;
    const float* av = (which ? att_dst : att_src) + h * D;
    const float* Wrow = Wgat + ((size_t)h * D + t) * D;
    float s = 0.f;
    for (int f = 0; f < D; ++f) s += Wrow[f] * av[f];
    (which ? wtil_d : wtil_s)[h * D + t] = s;
  }
}

// ---------------- x -> bf16 copy + attention dots + deg zeroing -----------------
__global__ __launch_bounds__(256) void k_xb(
    const float* __restrict__ x,
    const float* __restrict__ wtil_s, const float* __restrict__ wtil_d,
    unsigned short* __restrict__ xb, float* __restrict__ a_s, float* __restrict__ a_d,
    int* __restrict__ deg, int N)
{
  const int w = threadIdx.x >> 6, l = threadIdx.x & 63;
  const int n = blockIdx.x * 4 + w;
  if (n >= N) return;
  if (l == 0) deg[n] = 0;   // replaces hipMemsetAsync (runs before k_deg on stream)
  float2 xv = ((const float2*)(x + (size_t)n * D))[l];
  ushort2 p; p.x = f2bf(xv.x); p.y = f2bf(xv.y);
  *(ushort2*)(xb + (size_t)n * D + 2 * l) = p;
  float s0 = xv.x * wtil_s[2*l]       + xv.y * wtil_s[2*l+1];
  float s1 = xv.x * wtil_s[D+2*l]     + xv.y * wtil_s[D+2*l+1];
  float s2 = xv.x * wtil_s[2*D+2*l]   + xv.y * wtil_s[2*D+2*l+1];
  float s3 = xv.x * wtil_s[3*D+2*l]   + xv.y * wtil_s[3*D+2*l+1];
  float d0 = xv.x * wtil_d[2*l]       + xv.y * wtil_d[2*l+1];
  float d1 = xv.x * wtil_d[D+2*l]     + xv.y * wtil_d[D+2*l+1];
  float d2 = xv.x * wtil_d[2*D+2*l]   + xv.y * wtil_d[2*D+2*l+1];
  float d3 = xv.x * wtil_d[3*D+2*l]   + xv.y * wtil_d[3*D+2*l+1];
  #pragma unroll
  for (int off = 32; off; off >>= 1) {
    s0 += __shfl_xor(s0, off); s1 += __shfl_xor(s1, off);
    s2 += __shfl_xor(s2, off); s3 += __shfl_xor(s3, off);
    d0 += __shfl_xor(d0, off); d1 += __shfl_xor(d1, off);
    d2 += __shfl_xor(d2, off); d3 += __shfl_xor(d3, off);
  }
  if (l == 0) {
    ((float4*)a_s)[n] = make_float4(s0, s1, s2, s3);
    ((float4*)a_d)[n] = make_float4(d0, d1, d2, d3);
  }
}

// ---------------- CSR build ----------------------------------------------------
__global__ void k_deg(const int* __restrict__ ei, int E, int N, int* __restrict__ deg)
{
  int e = blockIdx.x * blockDim.x + threadIdx.x;
  if (e >= E + N) return;
  int dst = (e < E) ? ei[E + e] : (e - E);
  atomicAdd(&deg[dst], 1);
}

__global__ void k_scan1(const int* __restrict__ deg, int N, int* __restrict__ bsum)
{
  __shared__ int s[256];
  int t = threadIdx.x;
  int i = blockIdx.x * 256 + t;
  s[t] = (i < N) ? deg[i] : 0;
  __syncthreads();
  for (int off = 128; off; off >>= 1) {
    if (t < off) s[t] += s[t + off];
    __syncthreads();
  }
  if (t == 0) bsum[blockIdx.x] = s[0];
}

__global__ void k_scan2(int* __restrict__ bsum, int nb)
{
  __shared__ int s[128];
  int t = threadIdx.x;
  int v = (t < nb) ? bsum[t] : 0;
  s[t] = v; __syncthreads();
  for (int off = 1; off < 128; off <<= 1) {
    int xv = (t >= off) ? s[t - off] : 0;
    __syncthreads();
    s[t] += xv;
    __syncthreads();
  }
  if (t < nb) bsum[t] = s[t] - v;   // exclusive
}

__global__ void k_scan3(const int* __restrict__ deg, const int* __restrict__ bsum,
                        int N, int Et, int* __restrict__ row_ptr,
                        int* __restrict__ cursor, float* __restrict__ dinv)
{
  __shared__ int s[256];
  int t = threadIdx.x;
  int i = blockIdx.x * 256 + t;
  int v = (i < N) ? deg[i] : 0;
  s[t] = v; __syncthreads();
  for (int off = 1; off < 256; off <<= 1) {
    int xv = (t >= off) ? s[t - off] : 0;
    __syncthreads();
    s[t] += xv;
    __syncthreads();
  }
  if (i < N) {
    int excl = s[t] - v + bsum[blockIdx.x];
    row_ptr[i] = excl;
    cursor[i] = excl;
    dinv[i] = rsqrtf((float)v);    // deg >= 1 (self-loop)
  }
  if (i == 0) row_ptr[N] = Et;
}

__global__ void k_fill(const int* __restrict__ ei, int E, int N,
                       int* __restrict__ cursor, int* __restrict__ col_src)
{
  int e = blockIdx.x * blockDim.x + threadIdx.x;
  if (e >= E + N) return;
  int src, dst;
  if (e < E) { src = ei[e]; dst = ei[E + e]; }
  else       { src = e - E; dst = src; }
  int pos = atomicAdd(&cursor[dst], 1);
  col_src[pos] = src;
}

// ---------------- x-domain aggregation ------------------------------------------
__global__ __launch_bounds__(256) void k_agg2(
    const unsigned short* __restrict__ xb,
    const float* __restrict__ a_s, const float* __restrict__ a_d,
    const int* __restrict__ row_ptr, const int* __restrict__ col_src,
    const float* __restrict__ dinv,
    unsigned short* __restrict__ UV, int N)
{
  __shared__ float4 sh_al[8][33];
  __shared__ int    sh_src[8][33];
  __shared__ float  sh_cf[8][33];
  const int hw = threadIdx.x >> 5, lh = threadIdx.x & 31;
  const int n = blockIdx.x * 8 + hw;
  if (n >= N) return;
  const int start = row_ptr[n], end = row_ptr[n + 1];
  const float4 adn = ((const float4*)a_d)[n];

  float den0 = 0.f, den1 = 0.f, den2 = 0.f, den3 = 0.f;
  float ug[4][4] = {};
  float vg[4] = {};

  for (int base = start; base < end; base += 32) {
    const int cnt = min(32, end - base);
    if (lh < cnt) {
      int s = col_src[base + lh];
      float4 as4 = ((const float4*)a_s)[s];
      float e0 = as4.x + adn.x; e0 = (e0 >= 0.f) ? e0 : NEG_SLOPE * e0;
      float e1 = as4.y + adn.y; e1 = (e1 >= 0.f) ? e1 : NEG_SLOPE * e1;
      float e2 = as4.z + adn.z; e2 = (e2 >= 0.f) ? e2 : NEG_SLOPE * e2;
      float e3 = as4.w + adn.w; e3 = (e3 >= 0.f) ? e3 : NEG_SLOPE * e3;
      float x0 = __expf(e0), x1 = __expf(e1), x2 = __expf(e2), x3 = __expf(e3);
      den0 += x0; den1 += x1; den2 += x2; den3 += x3;
      sh_al[hw][lh] = make_float4(x0, x1, x2, x3);
      sh_src[hw][lh] = s;
      sh_cf[hw][lh] = dinv[s];
    }
    if (lh == 0) {   // sentinel
      sh_al[hw][cnt] = make_float4(0.f, 0.f, 0.f, 0.f);
      sh_src[hw][cnt] = 0;
      sh_cf[hw][cnt] = 0.f;
    }
    for (int j = 0; j < cnt; j += 2) {
      float4 alA = sh_al[hw][j];     int sA = sh_src[hw][j];     float cfA = sh_cf[hw][j];
      float4 alB = sh_al[hw][j + 1]; int sB = sh_src[hw][j + 1]; float cfB = sh_cf[hw][j + 1];
      ushort4 xA = *(const ushort4*)(xb + ((size_t)sA << 7) + (lh << 2));
      ushort4 xB = *(const ushort4*)(xb + ((size_t)sB << 7) + (lh << 2));
      float fa[4] = {bf2f(xA.x), bf2f(xA.y), bf2f(xA.z), bf2f(xA.w)};
      float fb[4] = {bf2f(xB.x), bf2f(xB.y), bf2f(xB.z), bf2f(xB.w)};
      float aA[4] = {alA.x, alA.y, alA.z, alA.w};
      float aB[4] = {alB.x, alB.y, alB.z, alB.w};
      #pragma unroll
      for (int h = 0; h < 4; ++h)
        #pragma unroll
        for (int d = 0; d < 4; ++d)
          ug[h][d] += aA[h] * fa[d] + aB[h] * fb[d];
      #pragma unroll
      for (int d = 0; d < 4; ++d)
        vg[d] += cfA * fa[d] + cfB * fb[d];
    }
  }

  #pragma unroll
  for (int off = 16; off; off >>= 1) {
    den0 += __shfl_xor(den0, off); den1 += __shfl_xor(den1, off);
    den2 += __shfl_xor(den2, off); den3 += __shfl_xor(den3, off);
  }
  const float r[4] = {1.f / den0, 1.f / den1, 1.f / den2, 1.f / den3};
  const float dn = dinv[n];
  unsigned short* uvp = UV + (size_t)n * 640;
  #pragma unroll
  for (int h = 0; h < 4; ++h) {
    ushort4 u;
    u.x = f2bf(ug[h][0] * r[h]); u.y = f2bf(ug[h][1] * r[h]);
    u.z = f2bf(ug[h][2] * r[h]); u.w = f2bf(ug[h][3] * r[h]);
    *(ushort4*)(uvp + h * 128 + 4 * lh) = u;
  }
  ushort4 v4;
  v4.x = f2bf(vg[0] * dn); v4.y = f2bf(vg[1] * dn);
  v4.z = f2bf(vg[2] * dn); v4.w = f2bf(vg[3] * dn);
  *(ushort4*)(uvp + 512 + 4 * lh) = v4;
}

// ---------------- fused MFMA GEMM + gate + LayerNorm ----------------------------
// 235 blocks, 256 thr. Block = 128 rows x 256 out-cols (gat 128 + gcn 128).
// A (UV rows) staged ONCE per chunk; epilogue in-register (f32 accs), row = one
// 16-lane group (4-step shfl reductions). Epilogue consts in 4KB LDS table.
__global__ __launch_bounds__(256) void k_gemm3(
    const unsigned short* __restrict__ UV,
    const unsigned short* __restrict__ Wt2g, const unsigned short* __restrict__ Wt2c,
    const float* __restrict__ b_gat, const float* __restrict__ b_gcn,
    const float* __restrict__ W_gate, const float* __restrict__ b_gate,
    const float* __restrict__ gamma, const float* __restrict__ beta,
    float* __restrict__ out, int N)
{
  __shared__ unsigned short As[128 * 128];  // 32 KB, 16B-block kb ^= row&7
  __shared__ unsigned short Bs[128 * 128];  // 32 KB, 16B-block kb ^= col&7
  __shared__ float ec[8][128];              // 0:b_gat 1:b_gcn 2:Wg0g 3:Wg1g 4:Wg0c 5:Wg1c 6:gamma 7:beta
  const int t = threadIdx.x;
  const int m0 = blockIdx.x * 128;

  {
    int idx = t * 4;
    #pragma unroll
    for (int i = 0; i < 4; ++i) {
      int arr = (idx + i) >> 7, c = (idx + i) & 127;
      float v;
      switch (arr) {
        case 0: v = b_gat[c]; break;
        case 1: v = b_gcn[c]; break;
        case 2: v = W_gate[2 * c]; break;
        case 3: v = W_gate[2 * c + 1]; break;
        case 4: v = W_gate[256 + 2 * c]; break;
        case 5: v = W_gate[256 + 2 * c + 1]; break;
        case 6: v = gamma[c]; break;
        default: v = beta[c]; break;
      }
      ec[arr][c] = v;
    }
  }

  const int w = t >> 6, l = t & 63;
  const int lrow = l & 15, lk = l >> 4;

  f32x4 accg[2][8], accc[2][8];
  #pragma unroll
  for (int m = 0; m < 2; ++m)
    #pragma unroll
    for (int n = 0; n < 8; ++n) {
      accg[m][n] = (f32x4){0.f, 0.f, 0.f, 0.f};
      accc[m][n] = (f32x4){0.f, 0.f, 0.f, 0.f};
    }

  // ---- 4 gat chunks (K=512), then 1 gcn chunk (K=128, A at UV offset 512) ----
  for (int kc = 0; kc < 5; ++kc) {
    const int abase = (kc < 4) ? kc * 128 : 512;
    __syncthreads();
    #pragma unroll
    for (int i = 0; i < 8; ++i) {
      int g = i * 256 + t;
      int row = g >> 4, kb = g & 15;
      int gr = m0 + row;
      uint4 v = make_uint4(0u, 0u, 0u, 0u);
      if (gr < N) v = *(const uint4*)(UV + (size_t)gr * 640 + abase + kb * 8);
      *(uint4*)&As[row * 128 + ((kb ^ (row & 7)) << 3)] = v;
    }
    #pragma unroll
    for (int i = 0; i < 8; ++i) {
      int g = i * 256 + t;
      int col = g >> 4, kb = g & 15;
      uint4 v = (kc < 4)
        ? *(const uint4*)(Wt2g + (size_t)col * 512 + kc * 128 + kb * 8)
        : *(const uint4*)(Wt2c + (size_t)col * 128 + kb * 8);
      *(uint4*)&Bs[col * 128 + ((kb ^ (col & 7)) << 3)] = v;
    }
    __syncthreads();
    if (kc < 4) {
      #pragma unroll
      for (int ks = 0; ks < 4; ++ks) {
        int kb = ks * 4 + lk;
        bf16x8 a[2], b[8];
        #pragma unroll
        for (int m = 0; m < 2; ++m) {
          int row = w * 32 + m * 16 + lrow;
          a[m] = *(const bf16x8*)&As[row * 128 + ((kb ^ (row & 7)) << 3)];
        }
        #pragma unroll
        for (int n = 0; n < 8; ++n) {
          int col = n * 16 + lrow;
          b[n] = *(const bf16x8*)&Bs[col * 128 + ((kb ^ (col & 7)) << 3)];
        }
        #pragma unroll
        for (int m = 0; m < 2; ++m)
          #pragma unroll
          for (int n = 0; n < 8; ++n)
            accg[m][n] = __builtin_amdgcn_mfma_f32_16x16x32_bf16(a[m], b[n], accg[m][n], 0, 0, 0);
      }
    } else {
      #pragma unroll
      for (int ks = 0; ks < 4; ++ks) {
        int kb = ks * 4 + lk;
        bf16x8 a[2], b[8];
        #pragma unroll
        for (int m = 0; m < 2; ++m) {
          int row = w * 32 + m * 16 + lrow;
          a[m] = *(const bf16x8*)&As[row * 128 + ((kb ^ (row & 7)) << 3)];
        }
        #pragma unroll
        for (int n = 0; n < 8; ++n) {
          int col = n * 16 + lrow;
          b[n] = *(const bf16x8*)&Bs[col * 128 + ((kb ^ (col & 7)) << 3)];
        }
        #pragma unroll
        for (int m = 0; m < 2; ++m)
          #pragma unroll
          for (int n = 0; n < 8; ++n)
            accc[m][n] = __builtin_amdgcn_mfma_f32_16x16x32_bf16(a[m], b[n], accc[m][n], 0, 0, 0);
      }
    }
  }

  // ---- epilogue: gate + residual + LayerNorm, row = 16-lane group -------------
  const float bg0 = b_gate[0], bg1 = b_gate[1];
  #pragma unroll
  for (int m = 0; m < 2; ++m) {
    #pragma unroll
    for (int j = 0; j < 4; ++j) {
      const int r = m0 + w * 32 + m * 16 + lk * 4 + j;
      float ga[8], gc[8];
      float z0 = 0.f, z1 = 0.f;
      #pragma unroll
      for (int n = 0; n < 8; ++n) {
        int c = n * 16 + lrow;
        ga[n] = accg[m][n][j] * 0.25f + ec[0][c];
        gc[n] = accc[m][n][j] + ec[1][c];
        z0 += ga[n] * ec[2][c] + gc[n] * ec[4][c];
        z1 += ga[n] * ec[3][c] + gc[n] * ec[5][c];
      }
      #pragma unroll
      for (int off = 8; off; off >>= 1) { z0 += __shfl_xor(z0, off); z1 += __shfl_xor(z1, off); }
      z0 += bg0; z1 += bg1;
      float mz = fmaxf(z0, z1);
      float e0 = __expf(z0 - mz), e1 = __expf(z1 - mz);
      float inv = 1.f / (e0 + e1);
      float w0 = e0 * inv, w1 = e1 * inv;
      float h[8], ss = 0.f;
      #pragma unroll
      for (int n = 0; n < 8; ++n) { h[n] = (1.f + w0) * ga[n] + w1 * gc[n]; ss += h[n]; }
      #pragma unroll
      for (int off = 8; off; off >>= 1) ss += __shfl_xor(ss, off);
      float mu = ss * (1.f / 128.f);
      float vs = 0.f;
      #pragma unroll
      for (int n = 0; n < 8; ++n) { h[n] -= mu; vs += h[n] * h[n]; }
      #pragma unroll
      for (int off = 8; off; off >>= 1) vs += __shfl_xor(vs, off);
      float rstd = rsqrtf(vs * (1.f / 128.f) + LN_EPS);
      if (r < N) {
        #pragma unroll
        for (int n = 0; n < 8; ++n) {
          int c = n * 16 + lrow;
          out[(size_t)r * 128 + c] = h[n] * rstd * ec[6][c] + ec[7][c];
        }
      }
    }
  }
}

extern "C" void kernel_launch(void* const* d_in, const int* in_sizes, int n_in,
                              void* d_out, int out_size, void* d_ws, size_t ws_size,
                              hipStream_t stream)
{
  const float* x       = (const float*)d_in[0];
  const int*   ei      = (const int*)d_in[1];
  const float* Wgat    = (const float*)d_in[2];
  const float* att_src = (const float*)d_in[3];
  const float* att_dst = (const float*)d_in[4];
  const float* b_gat   = (const float*)d_in[5];
  const float* Wgcn    = (const float*)d_in[6];
  const float* b_gcn   = (const float*)d_in[7];
  const float* W_gate  = (const float*)d_in[8];
  const float* b_gate  = (const float*)d_in[9];
  const float* gamma   = (const float*)d_in[10];
  const float* beta    = (const float*)d_in[11];
  float* out = (float*)d_out;

  const int N  = in_sizes[0] / D;   // 30000
  const int E  = in_sizes[1] / 2;   // 480000
  const int Et = E + N;

  char* p = (char*)d_ws;
  unsigned short* xb   = (unsigned short*)p; p += (size_t)N * D * 2;        // 7.7MB
  unsigned short* UV   = (unsigned short*)p; p += (size_t)N * 640 * 2;      // 38.4MB
  unsigned short* Wt2g = (unsigned short*)p; p += (size_t)128 * 512 * 2;
  unsigned short* Wt2c = (unsigned short*)p; p += (size_t)128 * 128 * 2;
  float* wtil_s  = (float*)p; p += 512 * 4;
  float* wtil_d  = (float*)p; p += 512 * 4;
  float* a_s     = (float*)p; p += (size_t)N * NH * 4;
  float* a_d     = (float*)p; p += (size_t)N * NH * 4;
  float* dinv    = (float*)p; p += (size_t)N * 4;
  int* deg       = (int*)p;   p += (size_t)N * 4;
  int* row_ptr   = (int*)p;   p += (size_t)(N + 1) * 4;
  int* cursor    = (int*)p;   p += (size_t)N * 4;
  int* col_src   = (int*)p;   p += (size_t)Et * 4;
  int* bsum      = (int*)p;   p += 1024;

  k_prep<<<264, 128, 0, stream>>>(Wgat, Wgcn, att_src, att_dst,
                                   Wt2g, Wt2c, wtil_s, wtil_d);
  k_xb<<<(N + 3) / 4, 256, 0, stream>>>(x, wtil_s, wtil_d, xb, a_s, a_d, deg, N);
  k_deg<<<(Et + 255) / 256, 256, 0, stream>>>(ei, E, N, deg);
  int nb = (N + 255) / 256;
  k_scan1<<<nb, 256, 0, stream>>>(deg, N, bsum);
  k_scan2<<<1, 128, 0, stream>>>(bsum, nb);
  k_scan3<<<nb, 256, 0, stream>>>(deg, bsum, N, Et, row_ptr, cursor, dinv);
  k_fill<<<(Et + 255) / 256, 256, 0, stream>>>(ei, E, N, cursor, col_src);
  k_agg2<<<(N + 7) / 8, 256, 0, stream>>>(xb, a_s, a_d, row_ptr, col_src, dinv, UV, N);
  k_gemm3<<<(N + 127) / 128, 256, 0, stream>>>(UV, Wt2g, Wt2c, b_gat, b_gcn,
                                                W_gate, b_gate, gamma, beta, out, N);
  (void)n_in; (void)out_size; (void)ws_size;
}

// Round 10
// 131.851 us; speedup vs baseline: 1.7292x; 1.1029x over previous
//
#include <hip/hip_runtime.h>
#include <hip/hip_bf16.h>

#define D 128
#define NH 4
#define NEG_SLOPE 0.2f
#define LN_EPS 1e-5f

typedef __attribute__((ext_vector_type(4))) float f32x4;
typedef __attribute__((ext_vector_type(8))) short bf16x8;

__device__ __forceinline__ float bf2f(unsigned short u) {
  union { unsigned int i; float f; } c; c.i = ((unsigned int)u) << 16; return c.f;
}
__device__ __forceinline__ unsigned short f2bf(float f) {
  union { float f; unsigned int i; } c; c.f = f;
  unsigned int r = c.i + 0x7FFFu + ((c.i >> 16) & 1u);  // RNE
  return (unsigned short)(r >> 16);
}

// ---------------- weight prep + deg zeroing -------------------------------------
// blocks 0..127: Wt2g; 128..255: Wt2c; 256..263: wtil; 264..: deg[...]=0
__global__ __launch_bounds__(128) void k_prep(
    const float* __restrict__ Wgat, const float* __restrict__ Wgcn,
    const float* __restrict__ att_src, const float* __restrict__ att_dst,
    unsigned short* __restrict__ Wt2g, unsigned short* __restrict__ Wt2c,
    float* __restrict__ wtil_s, float* __restrict__ wtil_d,
    int* __restrict__ deg, int N)
{
  int c = blockIdx.x, t = threadIdx.x;
  if (c < 128) {
    #pragma unroll
    for (int i = 0; i < 4; ++i) {
      int k = t + i * 128;
      int h = k >> 7, kk = k & 127;
      Wt2g[c * 512 + k] = f2bf(Wgat[((size_t)h * D + kk) * D + c]);
    }
  } else if (c < 256) {
    int cc = c - 128;
    Wt2c[cc * 128 + t] = f2bf(Wgcn[(size_t)t * D + cc]);
  } else if (c < 264) {
    int b2 = c - 256;
    int h = b2 >> 1, which = b2 & 1;
    const float* av = (which ? att_dst : att_src) + h * D;
    const float* Wrow = Wgat + ((size_t)h * D + t) * D;
    float s = 0.f;
    for (int f = 0; f < D; ++f) s += Wrow[f] * av[f];
    (which ? wtil_d : wtil_s)[h * D + t] = s;
  } else {
    int i = (c - 264) * 128 + t;
    if (i < N) deg[i] = 0;
  }
}

// ---------------- fused: x->bf16 + attention dots  ||  edge deg count -----------
// blocks [0, NBN): node work; blocks [NBN, NBN+NBE): edge atomics (deg pre-zeroed
// by k_prep, which runs strictly earlier on the stream).
__global__ __launch_bounds__(256) void k_xb_deg(
    const float* __restrict__ x,
    const float* __restrict__ wtil_s, const float* __restrict__ wtil_d,
    unsigned short* __restrict__ xb, float* __restrict__ a_s, float* __restrict__ a_d,
    const int* __restrict__ ei, int* __restrict__ deg,
    int N, int E, int NBN)
{
  if ((int)blockIdx.x >= NBN) {
    int e = (blockIdx.x - NBN) * 256 + threadIdx.x;
    if (e < E + N) {
      int dst = (e < E) ? ei[E + e] : (e - E);
      atomicAdd(&deg[dst], 1);
    }
    return;
  }
  const int w = threadIdx.x >> 6, l = threadIdx.x & 63;
  const int n = blockIdx.x * 4 + w;
  if (n >= N) return;
  float2 xv = ((const float2*)(x + (size_t)n * D))[l];
  ushort2 p; p.x = f2bf(xv.x); p.y = f2bf(xv.y);
  *(ushort2*)(xb + (size_t)n * D + 2 * l) = p;
  float s0 = xv.x * wtil_s[2*l]       + xv.y * wtil_s[2*l+1];
  float s1 = xv.x * wtil_s[D+2*l]     + xv.y * wtil_s[D+2*l+1];
  float s2 = xv.x * wtil_s[2*D+2*l]   + xv.y * wtil_s[2*D+2*l+1];
  float s3 = xv.x * wtil_s[3*D+2*l]   + xv.y * wtil_s[3*D+2*l+1];
  float d0 = xv.x * wtil_d[2*l]       + xv.y * wtil_d[2*l+1];
  float d1 = xv.x * wtil_d[D+2*l]     + xv.y * wtil_d[D+2*l+1];
  float d2 = xv.x * wtil_d[2*D+2*l]   + xv.y * wtil_d[2*D+2*l+1];
  float d3 = xv.x * wtil_d[3*D+2*l]   + xv.y * wtil_d[3*D+2*l+1];
  #pragma unroll
  for (int off = 32; off; off >>= 1) {
    s0 += __shfl_xor(s0, off); s1 += __shfl_xor(s1, off);
    s2 += __shfl_xor(s2, off); s3 += __shfl_xor(s3, off);
    d0 += __shfl_xor(d0, off); d1 += __shfl_xor(d1, off);
    d2 += __shfl_xor(d2, off); d3 += __shfl_xor(d3, off);
  }
  if (l == 0) {
    ((float4*)a_s)[n] = make_float4(s0, s1, s2, s3);
    ((float4*)a_d)[n] = make_float4(d0, d1, d2, d3);
  }
}

// ---------------- CSR scan + fill ----------------------------------------------
__global__ void k_scan1(const int* __restrict__ deg, int N, int* __restrict__ bsum)
{
  __shared__ int s[256];
  int t = threadIdx.x;
  int i = blockIdx.x * 256 + t;
  s[t] = (i < N) ? deg[i] : 0;
  __syncthreads();
  for (int off = 128; off; off >>= 1) {
    if (t < off) s[t] += s[t + off];
    __syncthreads();
  }
  if (t == 0) bsum[blockIdx.x] = s[0];
}

__global__ void k_scan2(int* __restrict__ bsum, int nb)
{
  __shared__ int s[128];
  int t = threadIdx.x;
  int v = (t < nb) ? bsum[t] : 0;
  s[t] = v; __syncthreads();
  for (int off = 1; off < 128; off <<= 1) {
    int xv = (t >= off) ? s[t - off] : 0;
    __syncthreads();
    s[t] += xv;
    __syncthreads();
  }
  if (t < nb) bsum[t] = s[t] - v;   // exclusive
}

__global__ void k_scan3(const int* __restrict__ deg, const int* __restrict__ bsum,
                        int N, int Et, int* __restrict__ row_ptr,
                        int* __restrict__ cursor, float* __restrict__ dinv)
{
  __shared__ int s[256];
  int t = threadIdx.x;
  int i = blockIdx.x * 256 + t;
  int v = (i < N) ? deg[i] : 0;
  s[t] = v; __syncthreads();
  for (int off = 1; off < 256; off <<= 1) {
    int xv = (t >= off) ? s[t - off] : 0;
    __syncthreads();
    s[t] += xv;
    __syncthreads();
  }
  if (i < N) {
    int excl = s[t] - v + bsum[blockIdx.x];
    row_ptr[i] = excl;
    cursor[i] = excl;
    dinv[i] = rsqrtf((float)v);    // deg >= 1 (self-loop)
  }
  if (i == 0) row_ptr[N] = Et;
}

__global__ void k_fill(const int* __restrict__ ei, int E, int N,
                       int* __restrict__ cursor, int* __restrict__ col_src)
{
  int e = blockIdx.x * blockDim.x + threadIdx.x;
  if (e >= E + N) return;
  int src, dst;
  if (e < E) { src = ei[e]; dst = ei[E + e]; }
  else       { src = e - E; dst = src; }
  int pos = atomicAdd(&cursor[dst], 1);
  col_src[pos] = src;
}

// ---------------- x-domain aggregation ------------------------------------------
__global__ __launch_bounds__(256) void k_agg2(
    const unsigned short* __restrict__ xb,
    const float* __restrict__ a_s, const float* __restrict__ a_d,
    const int* __restrict__ row_ptr, const int* __restrict__ col_src,
    const float* __restrict__ dinv,
    unsigned short* __restrict__ UV, int N)
{
  __shared__ float4 sh_al[8][33];
  __shared__ int    sh_src[8][33];
  __shared__ float  sh_cf[8][33];
  const int hw = threadIdx.x >> 5, lh = threadIdx.x & 31;
  const int n = blockIdx.x * 8 + hw;
  if (n >= N) return;
  const int start = row_ptr[n], end = row_ptr[n + 1];
  const float4 adn = ((const float4*)a_d)[n];

  float den0 = 0.f, den1 = 0.f, den2 = 0.f, den3 = 0.f;
  float ug[4][4] = {};
  float vg[4] = {};

  for (int base = start; base < end; base += 32) {
    const int cnt = min(32, end - base);
    if (lh < cnt) {
      int s = col_src[base + lh];
      float4 as4 = ((const float4*)a_s)[s];
      float e0 = as4.x + adn.x; e0 = (e0 >= 0.f) ? e0 : NEG_SLOPE * e0;
      float e1 = as4.y + adn.y; e1 = (e1 >= 0.f) ? e1 : NEG_SLOPE * e1;
      float e2 = as4.z + adn.z; e2 = (e2 >= 0.f) ? e2 : NEG_SLOPE * e2;
      float e3 = as4.w + adn.w; e3 = (e3 >= 0.f) ? e3 : NEG_SLOPE * e3;
      float x0 = __expf(e0), x1 = __expf(e1), x2 = __expf(e2), x3 = __expf(e3);
      den0 += x0; den1 += x1; den2 += x2; den3 += x3;
      sh_al[hw][lh] = make_float4(x0, x1, x2, x3);
      sh_src[hw][lh] = s;
      sh_cf[hw][lh] = dinv[s];
    }
    if (lh == 0) {   // sentinel
      sh_al[hw][cnt] = make_float4(0.f, 0.f, 0.f, 0.f);
      sh_src[hw][cnt] = 0;
      sh_cf[hw][cnt] = 0.f;
    }
    for (int j = 0; j < cnt; j += 2) {
      float4 alA = sh_al[hw][j];     int sA = sh_src[hw][j];     float cfA = sh_cf[hw][j];
      float4 alB = sh_al[hw][j + 1]; int sB = sh_src[hw][j + 1]; float cfB = sh_cf[hw][j + 1];
      ushort4 xA = *(const ushort4*)(xb + ((size_t)sA << 7) + (lh << 2));
      ushort4 xB = *(const ushort4*)(xb + ((size_t)sB << 7) + (lh << 2));
      float fa[4] = {bf2f(xA.x), bf2f(xA.y), bf2f(xA.z), bf2f(xA.w)};
      float fb[4] = {bf2f(xB.x), bf2f(xB.y), bf2f(xB.z), bf2f(xB.w)};
      float aA[4] = {alA.x, alA.y, alA.z, alA.w};
      float aB[4] = {alB.x, alB.y, alB.z, alB.w};
      #pragma unroll
      for (int h = 0; h < 4; ++h)
        #pragma unroll
        for (int d = 0; d < 4; ++d)
          ug[h][d] += aA[h] * fa[d] + aB[h] * fb[d];
      #pragma unroll
      for (int d = 0; d < 4; ++d)
        vg[d] += cfA * fa[d] + cfB * fb[d];
    }
  }

  #pragma unroll
  for (int off = 16; off; off >>= 1) {
    den0 += __shfl_xor(den0, off); den1 += __shfl_xor(den1, off);
    den2 += __shfl_xor(den2, off); den3 += __shfl_xor(den3, off);
  }
  const float r[4] = {1.f / den0, 1.f / den1, 1.f / den2, 1.f / den3};
  const float dn = dinv[n];
  unsigned short* uvp = UV + (size_t)n * 640;
  #pragma unroll
  for (int h = 0; h < 4; ++h) {
    ushort4 u;
    u.x = f2bf(ug[h][0] * r[h]); u.y = f2bf(ug[h][1] * r[h]);
    u.z = f2bf(ug[h][2] * r[h]); u.w = f2bf(ug[h][3] * r[h]);
    *(ushort4*)(uvp + h * 128 + 4 * lh) = u;
  }
  ushort4 v4;
  v4.x = f2bf(vg[0] * dn); v4.y = f2bf(vg[1] * dn);
  v4.z = f2bf(vg[2] * dn); v4.w = f2bf(vg[3] * dn);
  *(ushort4*)(uvp + 512 + 4 * lh) = v4;
}

// ---------------- fused MFMA GEMM + gate + LayerNorm (BM=64) --------------------
// 469 blocks, 256 thr. Block = 64 rows x 256 out-cols. LDS 52KB -> 3 blocks/CU.
// Wave w owns rows w*16..w*16+15 (one M-frag); 8 gat + 8 gcn col-frags in f32.
__global__ __launch_bounds__(256) void k_gemm3(
    const unsigned short* __restrict__ UV,
    const unsigned short* __restrict__ Wt2g, const unsigned short* __restrict__ Wt2c,
    const float* __restrict__ b_gat, const float* __restrict__ b_gcn,
    const float* __restrict__ W_gate, const float* __restrict__ b_gate,
    const float* __restrict__ gamma, const float* __restrict__ beta,
    float* __restrict__ out, int N)
{
  __shared__ unsigned short As[64 * 128];   // 16 KB, kb ^= row&7
  __shared__ unsigned short Bs[128 * 128];  // 32 KB, kb ^= col&7
  __shared__ float ec[8][128];              // 0:b_gat 1:b_gcn 2:Wg0g 3:Wg1g 4:Wg0c 5:Wg1c 6:gamma 7:beta
  const int t = threadIdx.x;
  const int m0 = blockIdx.x * 64;

  {
    int idx = t * 4;
    #pragma unroll
    for (int i = 0; i < 4; ++i) {
      int arr = (idx + i) >> 7, c = (idx + i) & 127;
      float v;
      switch (arr) {
        case 0: v = b_gat[c]; break;
        case 1: v = b_gcn[c]; break;
        case 2: v = W_gate[2 * c]; break;
        case 3: v = W_gate[2 * c + 1]; break;
        case 4: v = W_gate[256 + 2 * c]; break;
        case 5: v = W_gate[256 + 2 * c + 1]; break;
        case 6: v = gamma[c]; break;
        default: v = beta[c]; break;
      }
      ec[arr][c] = v;
    }
  }

  const int w = t >> 6, l = t & 63;
  const int lrow = l & 15, lk = l >> 4;
  const int arow = w * 16 + lrow;

  f32x4 accg[8], accc[8];
  #pragma unroll
  for (int n = 0; n < 8; ++n) {
    accg[n] = (f32x4){0.f, 0.f, 0.f, 0.f};
    accc[n] = (f32x4){0.f, 0.f, 0.f, 0.f};
  }

  // ---- 4 gat chunks (K=512), then 1 gcn chunk (K=128, A at UV offset 512) ----
  for (int kc = 0; kc < 5; ++kc) {
    const int abase = (kc < 4) ? kc * 128 : 512;
    __syncthreads();
    #pragma unroll
    for (int i = 0; i < 4; ++i) {        // A: 64 rows x 16 kb = 1024 uint4
      int g = i * 256 + t;
      int row = g >> 4, kb = g & 15;
      int gr = m0 + row;
      uint4 v = make_uint4(0u, 0u, 0u, 0u);
      if (gr < N) v = *(const uint4*)(UV + (size_t)gr * 640 + abase + kb * 8);
      *(uint4*)&As[row * 128 + ((kb ^ (row & 7)) << 3)] = v;
    }
    #pragma unroll
    for (int i = 0; i < 8; ++i) {        // B: 128 cols x 16 kb = 2048 uint4
      int g = i * 256 + t;
      int col = g >> 4, kb = g & 15;
      uint4 v = (kc < 4)
        ? *(const uint4*)(Wt2g + (size_t)col * 512 + kc * 128 + kb * 8)
        : *(const uint4*)(Wt2c + (size_t)col * 128 + kb * 8);
      *(uint4*)&Bs[col * 128 + ((kb ^ (col & 7)) << 3)] = v;
    }
    __syncthreads();
    f32x4* acc = (kc < 4) ? accg : accc;
    #pragma unroll
    for (int ks = 0; ks < 4; ++ks) {
      int kb = ks * 4 + lk;
      bf16x8 a = *(const bf16x8*)&As[arow * 128 + ((kb ^ (arow & 7)) << 3)];
      #pragma unroll
      for (int n = 0; n < 8; ++n) {
        int col = n * 16 + lrow;
        bf16x8 b = *(const bf16x8*)&Bs[col * 128 + ((kb ^ (col & 7)) << 3)];
        acc[n] = __builtin_amdgcn_mfma_f32_16x16x32_bf16(a, b, acc[n], 0, 0, 0);
      }
    }
  }

  // ---- epilogue: gate + residual + LayerNorm, row = 16-lane group -------------
  const float bg0 = b_gate[0], bg1 = b_gate[1];
  #pragma unroll
  for (int j = 0; j < 4; ++j) {
    const int r = m0 + w * 16 + lk * 4 + j;
    float ga[8], gc[8];
    float z0 = 0.f, z1 = 0.f;
    #pragma unroll
    for (int n = 0; n < 8; ++n) {
      int c = n * 16 + lrow;
      ga[n] = accg[n][j] * 0.25f + ec[0][c];
      gc[n] = accc[n][j] + ec[1][c];
      z0 += ga[n] * ec[2][c] + gc[n] * ec[4][c];
      z1 += ga[n] * ec[3][c] + gc[n] * ec[5][c];
    }
    #pragma unroll
    for (int off = 8; off; off >>= 1) { z0 += __shfl_xor(z0, off); z1 += __shfl_xor(z1, off); }
    z0 += bg0; z1 += bg1;
    float mz = fmaxf(z0, z1);
    float e0 = __expf(z0 - mz), e1 = __expf(z1 - mz);
    float inv = 1.f / (e0 + e1);
    float w0 = e0 * inv, w1 = e1 * inv;
    float h[8], ss = 0.f;
    #pragma unroll
    for (int n = 0; n < 8; ++n) { h[n] = (1.f + w0) * ga[n] + w1 * gc[n]; ss += h[n]; }
    #pragma unroll
    for (int off = 8; off; off >>= 1) ss += __shfl_xor(ss, off);
    float mu = ss * (1.f / 128.f);
    float vs = 0.f;
    #pragma unroll
    for (int n = 0; n < 8; ++n) { h[n] -= mu; vs += h[n] * h[n]; }
    #pragma unroll
    for (int off = 8; off; off >>= 1) vs += __shfl_xor(vs, off);
    float rstd = rsqrtf(vs * (1.f / 128.f) + LN_EPS);
    if (r < N) {
      #pragma unroll
      for (int n = 0; n < 8; ++n) {
        int c = n * 16 + lrow;
        out[(size_t)r * 128 + c] = h[n] * rstd * ec[6][c] + ec[7][c];
      }
    }
  }
}

extern "C" void kernel_launch(void* const* d_in, const int* in_sizes, int n_in,
                              void* d_out, int out_size, void* d_ws, size_t ws_size,
                              hipStream_t stream)
{
  const float* x       = (const float*)d_in[0];
  const int*   ei      = (const int*)d_in[1];
  const float* Wgat    = (const float*)d_in[2];
  const float* att_src = (const float*)d_in[3];
  const float* att_dst = (const float*)d_in[4];
  const float* b_gat   = (const float*)d_in[5];
  const float* Wgcn    = (const float*)d_in[6];
  const float* b_gcn   = (const float*)d_in[7];
  const float* W_gate  = (const float*)d_in[8];
  const float* b_gate  = (const float*)d_in[9];
  const float* gamma   = (const float*)d_in[10];
  const float* beta    = (const float*)d_in[11];
  float* out = (float*)d_out;

  const int N  = in_sizes[0] / D;   // 30000
  const int E  = in_sizes[1] / 2;   // 480000
  const int Et = E + N;

  char* p = (char*)d_ws;
  unsigned short* xb   = (unsigned short*)p; p += (size_t)N * D * 2;        // 7.7MB
  unsigned short* UV   = (unsigned short*)p; p += (size_t)N * 640 * 2;      // 38.4MB
  unsigned short* Wt2g = (unsigned short*)p; p += (size_t)128 * 512 * 2;
  unsigned short* Wt2c = (unsigned short*)p; p += (size_t)128 * 128 * 2;
  float* wtil_s  = (float*)p; p += 512 * 4;
  float* wtil_d  = (float*)p; p += 512 * 4;
  float* a_s     = (float*)p; p += (size_t)N * NH * 4;
  float* a_d     = (float*)p; p += (size_t)N * NH * 4;
  float* dinv    = (float*)p; p += (size_t)N * 4;
  int* deg       = (int*)p;   p += (size_t)N * 4;
  int* row_ptr   = (int*)p;   p += (size_t)(N + 1) * 4;
  int* cursor    = (int*)p;   p += (size_t)N * 4;
  int* col_src   = (int*)p;   p += (size_t)Et * 4;
  int* bsum      = (int*)p;   p += 1024;

  const int NBN = (N + 3) / 4;                 // node blocks in k_xb_deg
  const int NBE = (Et + 255) / 256;            // edge blocks in k_xb_deg

  k_prep<<<264 + (N + 127) / 128, 128, 0, stream>>>(
      Wgat, Wgcn, att_src, att_dst, Wt2g, Wt2c, wtil_s, wtil_d, deg, N);
  k_xb_deg<<<NBN + NBE, 256, 0, stream>>>(x, wtil_s, wtil_d, xb, a_s, a_d,
                                           ei, deg, N, E, NBN);
  int nb = (N + 255) / 256;
  k_scan1<<<nb, 256, 0, stream>>>(deg, N, bsum);
  k_scan2<<<1, 128, 0, stream>>>(bsum, nb);
  k_scan3<<<nb, 256, 0, stream>>>(deg, bsum, N, Et, row_ptr, cursor, dinv);
  k_fill<<<(Et + 255) / 256, 256, 0, stream>>>(ei, E, N, cursor, col_src);
  k_agg2<<<(N + 7) / 8, 256, 0, stream>>>(xb, a_s, a_d, row_ptr, col_src, dinv, UV, N);
  k_gemm3<<<(N + 63) / 64, 256, 0, stream>>>(UV, Wt2g, Wt2c, b_gat, b_gcn,
                                              W_gate, b_gate, gamma, beta, out, N);
  (void)n_in; (void)out_size; (void)ws_size;
}